// Round 2
// baseline (14485.072 us; speedup 1.0000x reference)
//
#include <hip/hip_runtime.h>
#include <math.h>

#define DD 384
#define HH 12
#define DKK 32
#define LL 6
#define FFF 1536
#define BB 64
#define SS 512
#define MROWS (BB*SS)   // 32768

__device__ __forceinline__ float sigmoidf_(float x){ return 1.0f/(1.0f+expf(-x)); }

// ---------------- embedding + LN ----------------
__global__ __launch_bounds__(256) void embed_ln_kernel(
    const int* __restrict__ ids, const float* __restrict__ we,
    const float* __restrict__ pe, const float* __restrict__ te,
    const float* __restrict__ w, const float* __restrict__ b,
    float* __restrict__ x)
{
  int wv = threadIdx.x >> 6, lane = threadIdx.x & 63;
  int row = blockIdx.x * 4 + wv;
  int s = row & (SS-1);
  int id = ids[row];
  const float* wep = we + (size_t)id * DD;
  const float* pep = pe + (size_t)s * DD;
  float vals[6]; float sum = 0.f;
  #pragma unroll
  for (int i=0;i<6;i++){ int d = lane + 64*i; vals[i] = wep[d] + pep[d] + te[d]; sum += vals[i]; }
  #pragma unroll
  for (int off=32; off>=1; off>>=1) sum += __shfl_xor(sum, off);
  float mean = sum * (1.0f/DD);
  float vs = 0.f;
  #pragma unroll
  for (int i=0;i<6;i++){ float dv = vals[i]-mean; vs += dv*dv; }
  #pragma unroll
  for (int off=32; off>=1; off>>=1) vs += __shfl_xor(vs, off);
  float inv = rsqrtf(vs*(1.0f/DD) + 1e-12f);
  float* xr = x + (size_t)row*DD;
  #pragma unroll
  for (int i=0;i<6;i++){ int d = lane + 64*i; xr[d] = (vals[i]-mean)*inv*w[d] + b[d]; }
}

// ---------------- x = LN(x + y) ----------------
__global__ __launch_bounds__(256) void add_ln_kernel(
    float* __restrict__ x, const float* __restrict__ y,
    const float* __restrict__ w, const float* __restrict__ b)
{
  int wv = threadIdx.x >> 6, lane = threadIdx.x & 63;
  int row = blockIdx.x * 4 + wv;
  float* xr = x + (size_t)row*DD;
  const float* yr = y + (size_t)row*DD;
  float vals[6]; float sum = 0.f;
  #pragma unroll
  for (int i=0;i<6;i++){ int d = lane + 64*i; vals[i] = xr[d] + yr[d]; sum += vals[i]; }
  #pragma unroll
  for (int off=32; off>=1; off>>=1) sum += __shfl_xor(sum, off);
  float mean = sum * (1.0f/DD);
  float vs = 0.f;
  #pragma unroll
  for (int i=0;i<6;i++){ float dv = vals[i]-mean; vs += dv*dv; }
  #pragma unroll
  for (int off=32; off>=1; off>>=1) vs += __shfl_xor(vs, off);
  float inv = rsqrtf(vs*(1.0f/DD) + 1e-12f);
  #pragma unroll
  for (int i=0;i<6;i++){ int d = lane + 64*i; xr[d] = (vals[i]-mean)*inv*w[d] + b[d]; }
}

// ---------------- tiled fp32 GEMM: C = act(A @ B + bias) ----------------
// A: MxK row-major, B: KxN row-major. 64x64 tile, BK=16, 256 threads, 4x4/thread.
template<int ACT>
__global__ __launch_bounds__(256) void gemm_kernel(
    const float* __restrict__ A, const float* __restrict__ B,
    const float* __restrict__ bias, float* __restrict__ C,
    int M, int N, int K)
{
  __shared__ __align__(16) float As[16][68];
  __shared__ __align__(16) float Bs[16][68];
  int tid = threadIdx.x;
  int tx = tid & 15, ty = tid >> 4;
  int n0 = blockIdx.x * 64, m0 = blockIdx.y * 64;
  int am = tid >> 2, ak = (tid & 3) << 2;
  int bk = tid >> 4, bn = (tid & 15) << 2;
  const float* Ap = A + (size_t)(m0+am)*K + ak;
  const float* Bp = B + (size_t)bk*N + n0 + bn;
  float acc[4][4] = {};
  for (int k0=0; k0<K; k0+=16){
    float4 av = *(const float4*)(Ap + k0);
    float4 bv = *(const float4*)(Bp + (size_t)k0*N);
    As[ak+0][am]=av.x; As[ak+1][am]=av.y; As[ak+2][am]=av.z; As[ak+3][am]=av.w;
    *(float4*)&Bs[bk][bn] = bv;
    __syncthreads();
    #pragma unroll
    for (int kk=0;kk<16;kk++){
      float4 fa = *(const float4*)&As[kk][ty<<2];
      float4 fb = *(const float4*)&Bs[kk][tx<<2];
      float ar[4] = {fa.x,fa.y,fa.z,fa.w};
      float br[4] = {fb.x,fb.y,fb.z,fb.w};
      #pragma unroll
      for (int i=0;i<4;i++)
        #pragma unroll
        for (int j=0;j<4;j++) acc[i][j] += ar[i]*br[j];
    }
    __syncthreads();
  }
  float4 bz = *(const float4*)(bias + n0 + (tx<<2));
  float bs4[4] = {bz.x,bz.y,bz.z,bz.w};
  #pragma unroll
  for (int i=0;i<4;i++){
    float r[4];
    #pragma unroll
    for (int j=0;j<4;j++){
      float vvv = acc[i][j] + bs4[j];
      if (ACT==1) vvv = 0.5f*vvv*(1.0f+erff(vvv*0.70710678118f));
      r[j]=vvv;
    }
    float4 o; o.x=r[0]; o.y=r[1]; o.z=r[2]; o.w=r[3];
    *(float4*)(C + (size_t)(m0 + (ty<<2) + i)*N + n0 + (tx<<2)) = o;
  }
}

// ---------------- beta/g projections (N=12 each), sigmoid (+mask for beta) ----------------
__global__ __launch_bounds__(256) void betag_kernel(
    const float* __restrict__ x, const float* __restrict__ Wb, const float* __restrict__ bb,
    const float* __restrict__ Wg, const float* __restrict__ bg,
    const int* __restrict__ mask, float* __restrict__ beta, float* __restrict__ g)
{
  __shared__ float Ws[384*25];   // [k][0..11]=Wb row k, [k][12..23]=Wg row k, stride 25
  for (int idx = threadIdx.x; idx < 384*12; idx += 256){
    int k = idx/12, j = idx - k*12;
    Ws[k*25+j]    = Wb[idx];
    Ws[k*25+12+j] = Wg[idx];
  }
  __syncthreads();
  int wv = threadIdx.x>>6, lane = threadIdx.x&63;
  int row = blockIdx.x*4 + wv;
  const float* xr = x + (size_t)row*DD;
  float accb[12], accg[12];
  #pragma unroll
  for (int j=0;j<12;j++){ accb[j]=0.f; accg[j]=0.f; }
  #pragma unroll
  for (int i=0;i<6;i++){
    int k = lane + 64*i;
    float xv = xr[k];
    const float* wr = &Ws[k*25];
    #pragma unroll
    for (int j=0;j<12;j++){ accb[j] += xv*wr[j]; accg[j] += xv*wr[12+j]; }
  }
  #pragma unroll
  for (int j=0;j<12;j++){
    #pragma unroll
    for (int off=32; off>=1; off>>=1){
      accb[j]+=__shfl_xor(accb[j],off);
      accg[j]+=__shfl_xor(accg[j],off);
    }
  }
  if (lane==0){
    float mk = (float)mask[row];
    #pragma unroll
    for (int j=0;j<12;j++){
      beta[(size_t)row*HH + j] = sigmoidf_(accb[j]+bb[j]) * mk;
      g[(size_t)row*HH + j]    = sigmoidf_(accg[j]+bg[j]);
    }
  }
}

// ---------------- k <- k / (||k||_2 + 1e-6), rows of 32 ----------------
__global__ __launch_bounds__(256) void knorm_kernel(float* __restrict__ k)
{
  int wv = threadIdx.x>>6, lane = threadIdx.x&63;
  int half = lane>>5, c = lane&31;
  int row = blockIdx.x*8 + wv*2 + half;
  float* kr = k + (size_t)row*DKK;
  float vv = kr[c];
  float ss = vv*vv;
  #pragma unroll
  for (int off=16; off>=1; off>>=1) ss += __shfl_xor(ss, off);
  kr[c] = vv / (sqrtf(ss) + 1e-6f);
}

// ---------------- DeltaNet dual-state recurrent scan ----------------
// One wave per (b,h). Lanes 0-31: fast state, 32-63: slow state. Lane owns col d=lane&31.
// q-in and out share ONE buffer (qo): q[t] is fully read before out[t] is written
// (wave-lockstep program order, same pointer => no reorder), distinct (b,h) slices
// across waves. NOT __restrict__ on qo by design.
__global__ __launch_bounds__(64) void scan_kernel(
  float* qo,
  const float* __restrict__ kp, const float* __restrict__ vp,
  const float* __restrict__ bp, const float* __restrict__ gp,
  const float* __restrict__ flp, const float* __restrict__ slp)
{
  int blk = blockIdx.x;
  int b = blk / HH, h = blk - b*HH;
  int lane = threadIdx.x;
  int col = lane & 31;
  float logit = (lane < 32) ? flp[h] : slp[h];
  float a = sigmoidf_(logit);
  float Sreg[32];
  #pragma unroll
  for (int j=0;j<32;j++) Sreg[j]=0.f;
  size_t base = ((size_t)b*SS)*DD + (size_t)h*DKK;
  float* qb = qo + base;
  const float* kb = kp + base;
  const float* vb = vp + base;
  const float* bbp = bp + (size_t)b*SS*HH + h;
  const float* gbp = gp + (size_t)b*SS*HH + h;
  for (int t=0;t<SS;t++){
    size_t o = (size_t)t*DD;
    float kt[32];
    #pragma unroll
    for (int j=0;j<32;j++) kt[j] = kb[o+j];     // wave-uniform
    float qt[32];
    #pragma unroll
    for (int j=0;j<32;j++) qt[j] = qb[o+j];     // wave-uniform
    float vt = vb[o+col];
    float bt = bbp[(size_t)t*HH];
    float gt = gbp[(size_t)t*HH];
    float r0=0.f,r1=0.f,r2=0.f,r3=0.f;
    #pragma unroll
    for (int j=0;j<32;j+=4){
      r0 += Sreg[j+0]*kt[j+0];
      r1 += Sreg[j+1]*kt[j+1];
      r2 += Sreg[j+2]*kt[j+2];
      r3 += Sreg[j+3]*kt[j+3];
    }
    float rf = (r0+r1)+(r2+r3);
    float c = bt*(vt - rf);
    #pragma unroll
    for (int j=0;j<32;j++) Sreg[j] = a*Sreg[j] + c*kt[j];
    float o0=0.f,o1=0.f,o2=0.f,o3=0.f;
    #pragma unroll
    for (int j=0;j<32;j+=4){
      o0 += Sreg[j+0]*qt[j+0];
      o1 += Sreg[j+1]*qt[j+1];
      o2 += Sreg[j+2]*qt[j+2];
      o3 += Sreg[j+3]*qt[j+3];
    }
    float of = (o0+o1)+(o2+o3);
    float other = __shfl_xor(of, 32);
    if (lane < 32){
      float res = gt*of + (1.0f-gt)*other;
      qb[o+col] = res;            // overwrite q[t] (already consumed)
    }
  }
}

// ---------------- masked mean-pool + L2 normalize ----------------
__global__ __launch_bounds__(384) void pool_kernel(
    const float* __restrict__ x, const int* __restrict__ mask, float* __restrict__ out)
{
  __shared__ float red[384];
  __shared__ float tot;
  int b = blockIdx.x, d = threadIdx.x;
  const float* xb = x + (size_t)b*SS*DD;
  const int* mb = mask + b*SS;
  float s=0.f, sm=0.f;
  for (int t=0;t<SS;t++){ float m=(float)mb[t]; s += xb[(size_t)t*DD+d]*m; sm += m; }
  float emb = s / fmaxf(sm, 1e-9f);
  red[d] = emb*emb;
  __syncthreads();
  for (int off=192; off>=3; off>>=1){
    if (d < off) red[d] += red[d+off];
    __syncthreads();
  }
  if (d==0) tot = red[0]+red[1]+red[2];
  __syncthreads();
  out[(size_t)b*DD + d] = emb * rsqrtf(tot);
}

extern "C" void kernel_launch(void* const* d_in, const int* in_sizes, int n_in,
                              void* d_out, int out_size, void* d_ws, size_t ws_size,
                              hipStream_t stream)
{
  const int*   ids  = (const int*)d_in[0];
  const int*   amask= (const int*)d_in[1];
  const float* we   = (const float*)d_in[2];
  const float* pe   = (const float*)d_in[3];
  const float* te   = (const float*)d_in[4];
  const float* elnw = (const float*)d_in[5];
  const float* elnb = (const float*)d_in[6];
  const float* Wq   = (const float*)d_in[7];
  const float* bq   = (const float*)d_in[8];
  const float* Wk   = (const float*)d_in[9];
  const float* bk   = (const float*)d_in[10];
  const float* Wv   = (const float*)d_in[11];
  const float* bv   = (const float*)d_in[12];
  const float* Wb   = (const float*)d_in[13];
  const float* bb   = (const float*)d_in[14];
  const float* Wg   = (const float*)d_in[15];
  const float* bgp  = (const float*)d_in[16];
  const float* Wo   = (const float*)d_in[17];
  const float* bo   = (const float*)d_in[18];
  const float* fl   = (const float*)d_in[19];
  const float* sl   = (const float*)d_in[20];
  const float* alnw = (const float*)d_in[21];
  const float* alnb = (const float*)d_in[22];
  const float* W1   = (const float*)d_in[23];
  const float* b1   = (const float*)d_in[24];
  const float* W2   = (const float*)d_in[25];
  const float* b2   = (const float*)d_in[26];
  const float* flnw = (const float*)d_in[27];
  const float* flnb = (const float*)d_in[28];
  float* out = (float*)d_out;
  float* w = (float*)d_ws;

  // workspace layout (floats) — total 51,118,080 floats = 204,472,320 bytes
  float* x    = w;                 // 12,582,912  (persistent activations)
  float* qb   = w + 12582912;      // 12,582,912  q -> attn-out (in-place) -> ffn2-out
  float* kb   = w + 25165824;      // 12,582,912  k -> o-proj-out -> ffn-hidden lo
  float* vb   = w + 37748736;      // 12,582,912  v -> ffn-hidden hi
  float* beta = w + 50331648;      //    393,216
  float* gbuf = w + 50724864;      //    393,216
  float* f2a  = kb;                // o-proj output (k dead after scan)
  float* hb   = kb;                // ffn hidden chunk: 25,165,824 floats spans kb+vb
  float* f2f  = qb;                // ffn2 output (q/attn dead after o-proj)

  embed_ln_kernel<<<MROWS/4, 256, 0, stream>>>(ids, we, pe, te, elnw, elnb, x);

  dim3 g6(6, 512);
  for (int l=0;l<LL;l++){
    const float* wq = Wq + (size_t)l*DD*DD;
    const float* wk = Wk + (size_t)l*DD*DD;
    const float* wv = Wv + (size_t)l*DD*DD;
    const float* wo = Wo + (size_t)l*DD*DD;
    gemm_kernel<0><<<g6,256,0,stream>>>(x, wq, bq + l*DD, qb, MROWS, DD, DD);
    gemm_kernel<0><<<g6,256,0,stream>>>(x, wk, bk + l*DD, kb, MROWS, DD, DD);
    gemm_kernel<0><<<g6,256,0,stream>>>(x, wv, bv + l*DD, vb, MROWS, DD, DD);
    betag_kernel<<<MROWS/4,256,0,stream>>>(x, Wb + (size_t)l*DD*HH, bb + l*HH,
                                           Wg + (size_t)l*DD*HH, bgp + l*HH,
                                           amask, beta, gbuf);
    knorm_kernel<<<MROWS*HH/8,256,0,stream>>>(kb);
    scan_kernel<<<BB*HH,64,0,stream>>>(qb, kb, vb, beta, gbuf, fl + l*HH, sl + l*HH);
    // o-proj: reads qb (attn out), writes kb (k dead)
    gemm_kernel<0><<<g6,256,0,stream>>>(qb, wo, bo + l*DD, f2a, MROWS, DD, DD);
    add_ln_kernel<<<MROWS/4,256,0,stream>>>(x, f2a, alnw + l*DD, alnb + l*DD);
    // FFN in 2 row-chunks of 16384; hidden (16384x1536) overlays kb+vb exactly
    for (int c=0;c<2;c++){
      const float* xa = x + (size_t)c*16384*DD;
      float* f2c = f2f + (size_t)c*16384*DD;
      gemm_kernel<1><<<dim3(24,256),256,0,stream>>>(xa, W1 + (size_t)l*DD*FFF, b1 + l*FFF, hb, 16384, FFF, DD);
      gemm_kernel<0><<<dim3(6,256),256,0,stream>>>(hb, W2 + (size_t)l*FFF*DD, b2 + l*DD, f2c, 16384, DD, FFF);
    }
    add_ln_kernel<<<MROWS/4,256,0,stream>>>(x, f2f, flnw + l*DD, flnb + l*DD);
  }

  pool_kernel<<<BB,384,0,stream>>>(x, amask, out);
}

// Round 3
// 6212.018 us; speedup vs baseline: 2.3318x; 2.3318x over previous
//
#include <hip/hip_runtime.h>
#include <math.h>

#define DD 384
#define HH 12
#define DKK 32
#define LL 6
#define FFF 1536
#define BB 64
#define SS 512
#define MROWS (BB*SS)   // 32768

typedef _Float16 f16;
typedef _Float16 half8 __attribute__((ext_vector_type(8)));
typedef float f32x4 __attribute__((ext_vector_type(4)));

__device__ __forceinline__ float sigmoidf_(float x){ return 1.0f/(1.0f+expf(-x)); }

__device__ __forceinline__ float h2f_lo(unsigned int u){
  union { unsigned short s; f16 h; } c; c.s = (unsigned short)(u & 0xffffu); return (float)c.h;
}
__device__ __forceinline__ float h2f_hi(unsigned int u){
  union { unsigned short s; f16 h; } c; c.s = (unsigned short)(u >> 16); return (float)c.h;
}

__device__ __forceinline__ void gl2lds16(const void* g, void* l){
  __builtin_amdgcn_global_load_lds((const __attribute__((address_space(1))) void*)g,
                                   (__attribute__((address_space(3))) void*)l, 16, 0, 0);
}

// ---------------- embedding + LN (writes fp32 x and f16 xh) ----------------
__global__ __launch_bounds__(256) void embed_ln_kernel(
    const int* __restrict__ ids, const float* __restrict__ we,
    const float* __restrict__ pe, const float* __restrict__ te,
    const float* __restrict__ w, const float* __restrict__ b,
    float* __restrict__ x, f16* __restrict__ xh)
{
  int wv = threadIdx.x >> 6, lane = threadIdx.x & 63;
  int row = blockIdx.x * 4 + wv;
  int s = row & (SS-1);
  int id = ids[row];
  const float* wep = we + (size_t)id * DD;
  const float* pep = pe + (size_t)s * DD;
  float vals[6]; float sum = 0.f;
  #pragma unroll
  for (int i=0;i<6;i++){ int d = lane + 64*i; vals[i] = wep[d] + pep[d] + te[d]; sum += vals[i]; }
  #pragma unroll
  for (int off=32; off>=1; off>>=1) sum += __shfl_xor(sum, off);
  float mean = sum * (1.0f/DD);
  float vs = 0.f;
  #pragma unroll
  for (int i=0;i<6;i++){ float dv = vals[i]-mean; vs += dv*dv; }
  #pragma unroll
  for (int off=32; off>=1; off>>=1) vs += __shfl_xor(vs, off);
  float inv = rsqrtf(vs*(1.0f/DD) + 1e-12f);
  float* xr = x + (size_t)row*DD;
  f16* xhr = xh + (size_t)row*DD;
  #pragma unroll
  for (int i=0;i<6;i++){ int d = lane + 64*i; float o = (vals[i]-mean)*inv*w[d] + b[d]; xr[d]=o; xhr[d]=(f16)o; }
}

// ---------------- x = LN(x + y); y is fp32 chunk starting at row0 ----------------
__global__ __launch_bounds__(256) void add_ln_kernel(
    float* __restrict__ x, f16* __restrict__ xh, const float* __restrict__ y,
    const float* __restrict__ w, const float* __restrict__ b, int row0)
{
  int wv = threadIdx.x >> 6, lane = threadIdx.x & 63;
  int row = row0 + blockIdx.x * 4 + wv;
  float* xr = x + (size_t)row*DD;
  f16* xhr = xh + (size_t)row*DD;
  const float* yr = y + (size_t)(blockIdx.x*4+wv)*DD;
  float vals[6]; float sum = 0.f;
  #pragma unroll
  for (int i=0;i<6;i++){ int d = lane + 64*i; vals[i] = xr[d] + yr[d]; sum += vals[i]; }
  #pragma unroll
  for (int off=32; off>=1; off>>=1) sum += __shfl_xor(sum, off);
  float mean = sum * (1.0f/DD);
  float vs = 0.f;
  #pragma unroll
  for (int i=0;i<6;i++){ float dv = vals[i]-mean; vs += dv*dv; }
  #pragma unroll
  for (int off=32; off>=1; off>>=1) vs += __shfl_xor(vs, off);
  float inv = rsqrtf(vs*(1.0f/DD) + 1e-12f);
  #pragma unroll
  for (int i=0;i<6;i++){ int d = lane + 64*i; float o = (vals[i]-mean)*inv*w[d] + b[d]; xr[d]=o; xhr[d]=(f16)o; }
}

// ---------------- weight transpose + f32->f16 (one layer: Wq,Wk,Wv,Wo,W1,W2) ----------------
// dst layout [N][K] f16 (B^T for the MFMA GEMM).
__global__ __launch_bounds__(256) void wtrans_kernel(
  const float* __restrict__ Wq, const float* __restrict__ Wk, const float* __restrict__ Wv,
  const float* __restrict__ Wo, const float* __restrict__ W1, const float* __restrict__ W2,
  f16* __restrict__ Wt)
{
  __shared__ float T[32][33];
  int bidx = blockIdx.x;
  const float* src; f16* dst; int K, N, tile;
  if (bidx < 576){ int m = bidx/144; tile = bidx - m*144; K=384; N=384;
    src = (m==0)?Wq:(m==1)?Wk:(m==2)?Wv:Wo; dst = Wt + m*147456; }
  else if (bidx < 1152){ tile = bidx-576; K=384; N=1536; src=W1; dst=Wt+589824; }
  else { tile = bidx-1152; K=1536; N=384; src=W2; dst=Wt+1179648; }
  int tN = N>>5;
  int tk = tile / tN, tn = tile - tk*tN;
  int k0 = tk<<5, n0 = tn<<5;
  int r = threadIdx.x >> 3, c4 = (threadIdx.x & 7) << 2;
  float4 vv = *(const float4*)(src + (size_t)(k0+r)*N + n0 + c4);
  T[r][c4+0]=vv.x; T[r][c4+1]=vv.y; T[r][c4+2]=vv.z; T[r][c4+3]=vv.w;
  __syncthreads();
  f16* dp = dst + (size_t)(n0+r)*K + k0 + c4;
  #pragma unroll
  for (int j=0;j<4;j++) dp[j] = (f16)T[c4+j][r];
}

// ---------------- f16 MFMA GEMM: C = act(A @ BT^T + bias) ----------------
// A: MxK row-major f16. BT: NxK row-major f16. 128x128 tile, BK=32, 256 thr (4 waves 2x2).
template<int ACT, int OUT16>
__global__ __launch_bounds__(256) void gemm_f16(
    const f16* __restrict__ A, const f16* __restrict__ BT,
    const float* __restrict__ bias, float* __restrict__ Cf, f16* __restrict__ Ch,
    int M, int N, int K)
{
  __shared__ __align__(16) f16 As[128*32];
  __shared__ __align__(16) f16 Bs[128*32];
  int tid = threadIdx.x, lane = tid & 63, wave = tid >> 6;
  int wm = wave >> 1, wn = wave & 1;
  int n0 = blockIdx.x * 128, m0 = blockIdx.y * 128;
  f32x4 acc[4][4] = {};
  int seg0 = wave*2048 + lane*16;
  int ar = lane & 15, kq = (lane >> 4) * 8;

  for (int k0=0; k0<K; k0+=32){
    #pragma unroll
    for (int i=0;i<2;i++){
      int seg = seg0 + i*1024;
      int e = seg >> 1; int row = e >> 5; int kk = e & 31;
      gl2lds16(A  + (size_t)(m0+row)*K + k0 + kk, (char*)As + seg);
      gl2lds16(BT + (size_t)(n0+row)*K + k0 + kk, (char*)Bs + seg);
    }
    __syncthreads();
    half8 af[4], bf[4];
    #pragma unroll
    for (int mi=0;mi<4;mi++) af[mi] = *(const half8*)&As[(wm*64 + mi*16 + ar)*32 + kq];
    #pragma unroll
    for (int ni=0;ni<4;ni++) bf[ni] = *(const half8*)&Bs[(wn*64 + ni*16 + ar)*32 + kq];
    #pragma unroll
    for (int mi=0;mi<4;mi++)
      #pragma unroll
      for (int ni=0;ni<4;ni++)
        acc[mi][ni] = __builtin_amdgcn_mfma_f32_16x16x32_f16(af[mi], bf[ni], acc[mi][ni], 0, 0, 0);
    __syncthreads();
  }
  int rb = (lane >> 4) * 4, cb = lane & 15;
  #pragma unroll
  for (int ni=0;ni<4;ni++){
    int cn = n0 + wn*64 + ni*16 + cb;
    float bz = bias[cn];
    #pragma unroll
    for (int mi=0;mi<4;mi++){
      int rm = m0 + wm*64 + mi*16 + rb;
      #pragma unroll
      for (int r=0;r<4;r++){
        float v = acc[mi][ni][r] + bz;
        if (ACT==1) v = 0.5f*v*(1.0f+erff(v*0.70710678118f));
        if (OUT16) Ch[(size_t)(rm+r)*N + cn] = (f16)v;
        else       Cf[(size_t)(rm+r)*N + cn] = v;
      }
    }
  }
}

// ---------------- beta/g projections (N=12 each), sigmoid (+mask for beta) ----------------
__global__ __launch_bounds__(256) void betag_kernel(
    const float* __restrict__ x, const float* __restrict__ Wb, const float* __restrict__ bb,
    const float* __restrict__ Wg, const float* __restrict__ bg,
    const int* __restrict__ mask, float* __restrict__ beta, float* __restrict__ g)
{
  __shared__ float Ws[384*25];
  for (int idx = threadIdx.x; idx < 384*12; idx += 256){
    int k = idx/12, j = idx - k*12;
    Ws[k*25+j]    = Wb[idx];
    Ws[k*25+12+j] = Wg[idx];
  }
  __syncthreads();
  int wv = threadIdx.x>>6, lane = threadIdx.x&63;
  int row = blockIdx.x*4 + wv;
  const float* xr = x + (size_t)row*DD;
  float accb[12], accg[12];
  #pragma unroll
  for (int j=0;j<12;j++){ accb[j]=0.f; accg[j]=0.f; }
  #pragma unroll
  for (int i=0;i<6;i++){
    int k = lane + 64*i;
    float xv = xr[k];
    const float* wr = &Ws[k*25];
    #pragma unroll
    for (int j=0;j<12;j++){ accb[j] += xv*wr[j]; accg[j] += xv*wr[12+j]; }
  }
  #pragma unroll
  for (int j=0;j<12;j++){
    #pragma unroll
    for (int off=32; off>=1; off>>=1){
      accb[j]+=__shfl_xor(accb[j],off);
      accg[j]+=__shfl_xor(accg[j],off);
    }
  }
  if (lane==0){
    float mk = (float)mask[row];
    #pragma unroll
    for (int j=0;j<12;j++){
      beta[(size_t)row*HH + j] = sigmoidf_(accb[j]+bb[j]) * mk;
      g[(size_t)row*HH + j]    = sigmoidf_(accg[j]+bg[j]);
    }
  }
}

// ---------------- k <- k / (||k||_2 + 1e-6), f16 rows of 32 ----------------
__global__ __launch_bounds__(256) void knorm_kernel(f16* __restrict__ k)
{
  int wv = threadIdx.x>>6, lane = threadIdx.x&63;
  int half_ = lane>>5, c = lane&31;
  int row = blockIdx.x*8 + wv*2 + half_;
  f16* kr = k + (size_t)row*DKK;
  float vv = (float)kr[c];
  float ss = vv*vv;
  #pragma unroll
  for (int off=16; off>=1; off>>=1) ss += __shfl_xor(ss, off);
  kr[c] = (f16)(vv / (sqrtf(ss) + 1e-6f));
}

// ---------------- DeltaNet dual-state recurrent scan (f16 q/k/v, in-place out into q) ----------------
__global__ __launch_bounds__(64) void scan_kernel(
  f16* qo,
  const f16* __restrict__ kp, const f16* __restrict__ vp,
  const float* __restrict__ bp, const float* __restrict__ gp,
  const float* __restrict__ flp, const float* __restrict__ slp)
{
  int blk = blockIdx.x;
  int b = blk / HH, h = blk - b*HH;
  int lane = threadIdx.x;
  int col = lane & 31;
  float logit = (lane < 32) ? flp[h] : slp[h];
  float a = sigmoidf_(logit);
  float Sreg[32];
  #pragma unroll
  for (int j=0;j<32;j++) Sreg[j]=0.f;
  size_t base = ((size_t)b*SS)*DD + (size_t)h*DKK;
  f16* qb = qo + base;
  const unsigned int* qu = (const unsigned int*)qb;     // aliases qb stores (no restrict)
  const unsigned int* ku = (const unsigned int*)(kp + base);
  const f16* vb = vp + base;
  const float* bbp = bp + (size_t)b*SS*HH + h;
  const float* gbp = gp + (size_t)b*SS*HH + h;
  for (int t=0;t<SS;t++){
    size_t o = (size_t)t*DD;
    size_t ou = o >> 1;
    float kt[32], qt[32];
    #pragma unroll
    for (int j=0;j<16;j++){
      unsigned int u = ku[ou+j];
      kt[2*j]   = h2f_lo(u);
      kt[2*j+1] = h2f_hi(u);
    }
    #pragma unroll
    for (int j=0;j<16;j++){
      unsigned int u = qu[ou+j];
      qt[2*j]   = h2f_lo(u);
      qt[2*j+1] = h2f_hi(u);
    }
    float vt = (float)vb[o+col];
    float bt = bbp[(size_t)t*HH];
    float gt = gbp[(size_t)t*HH];
    float r0=0.f,r1=0.f,r2=0.f,r3=0.f;
    #pragma unroll
    for (int j=0;j<32;j+=4){
      r0 += Sreg[j+0]*kt[j+0];
      r1 += Sreg[j+1]*kt[j+1];
      r2 += Sreg[j+2]*kt[j+2];
      r3 += Sreg[j+3]*kt[j+3];
    }
    float rf = (r0+r1)+(r2+r3);
    float c = bt*(vt - rf);
    #pragma unroll
    for (int j=0;j<32;j++) Sreg[j] = a*Sreg[j] + c*kt[j];
    float o0=0.f,o1=0.f,o2=0.f,o3=0.f;
    #pragma unroll
    for (int j=0;j<32;j+=4){
      o0 += Sreg[j+0]*qt[j+0];
      o1 += Sreg[j+1]*qt[j+1];
      o2 += Sreg[j+2]*qt[j+2];
      o3 += Sreg[j+3]*qt[j+3];
    }
    float of = (o0+o1)+(o2+o3);
    float other = __shfl_xor(of, 32);
    if (lane < 32){
      float res = gt*of + (1.0f-gt)*other;
      qb[o+col] = (f16)res;          // q[t] already consumed this iteration
    }
  }
}

// ---------------- masked mean-pool + L2 normalize ----------------
__global__ __launch_bounds__(384) void pool_kernel(
    const float* __restrict__ x, const int* __restrict__ mask, float* __restrict__ out)
{
  __shared__ float red[384];
  __shared__ float tot;
  int b = blockIdx.x, d = threadIdx.x;
  const float* xb = x + (size_t)b*SS*DD;
  const int* mb = mask + b*SS;
  float s=0.f, sm=0.f;
  for (int t=0;t<SS;t++){ float m=(float)mb[t]; s += xb[(size_t)t*DD+d]*m; sm += m; }
  float emb = s / fmaxf(sm, 1e-9f);
  red[d] = emb*emb;
  __syncthreads();
  for (int off=192; off>=3; off>>=1){
    if (d < off) red[d] += red[d+off];
    __syncthreads();
  }
  if (d==0) tot = red[0]+red[1]+red[2];
  __syncthreads();
  out[(size_t)b*DD + d] = emb * rsqrtf(tot);
}

extern "C" void kernel_launch(void* const* d_in, const int* in_sizes, int n_in,
                              void* d_out, int out_size, void* d_ws, size_t ws_size,
                              hipStream_t stream)
{
  const int*   ids  = (const int*)d_in[0];
  const int*   amask= (const int*)d_in[1];
  const float* we   = (const float*)d_in[2];
  const float* pe   = (const float*)d_in[3];
  const float* te   = (const float*)d_in[4];
  const float* elnw = (const float*)d_in[5];
  const float* elnb = (const float*)d_in[6];
  const float* Wq   = (const float*)d_in[7];
  const float* bq   = (const float*)d_in[8];
  const float* Wk   = (const float*)d_in[9];
  const float* bk   = (const float*)d_in[10];
  const float* Wv   = (const float*)d_in[11];
  const float* bv   = (const float*)d_in[12];
  const float* Wb   = (const float*)d_in[13];
  const float* bb   = (const float*)d_in[14];
  const float* Wg   = (const float*)d_in[15];
  const float* bgp  = (const float*)d_in[16];
  const float* Wo   = (const float*)d_in[17];
  const float* bo   = (const float*)d_in[18];
  const float* fl   = (const float*)d_in[19];
  const float* sl   = (const float*)d_in[20];
  const float* alnw = (const float*)d_in[21];
  const float* alnb = (const float*)d_in[22];
  const float* W1   = (const float*)d_in[23];
  const float* b1   = (const float*)d_in[24];
  const float* W2   = (const float*)d_in[25];
  const float* b2   = (const float*)d_in[26];
  const float* flnw = (const float*)d_in[27];
  const float* flnb = (const float*)d_in[28];
  float* out = (float*)d_out;
  float* w = (float*)d_ws;

  // workspace (float slots), total 44,924,928 floats = 179.7 MB
  float* x    = w;                      // 12,582,912 f
  f16*  xh   = (f16*)(w + 12582912);    // 12,582,912 h
  f16*  qh   = (f16*)(w + 18874368);    // 12,582,912 h  (attn out in-place)
  f16*  kh   = (f16*)(w + 25165824);    // 12,582,912 h
  f16*  vh   = (f16*)(w + 31457280);    // 12,582,912 h
  float* f2   = w + 37748736;           //  6,291,456 f  (chunk out; beta/g overlay)
  float* beta = f2;                     //    393,216 f
  float* gbuf = f2 + 393216;            //    393,216 f
  f16*  wt   = (f16*)(w + 44040192);    //  1,769,472 h
  f16*  hbf  = qh;                      // FFN hidden chunk 16384x1536 h = qh+kh region

  embed_ln_kernel<<<MROWS/4, 256, 0, stream>>>(ids, we, pe, te, elnw, elnb, x, xh);

  for (int l=0;l<LL;l++){
    wtrans_kernel<<<1728,256,0,stream>>>(
        Wq + (size_t)l*147456, Wk + (size_t)l*147456, Wv + (size_t)l*147456,
        Wo + (size_t)l*147456, W1 + (size_t)l*589824, W2 + (size_t)l*589824, wt);

    gemm_f16<0,1><<<dim3(3,256),256,0,stream>>>(xh, wt,          bq+l*DD, nullptr, qh, MROWS, DD, DD);
    gemm_f16<0,1><<<dim3(3,256),256,0,stream>>>(xh, wt+147456,   bk+l*DD, nullptr, kh, MROWS, DD, DD);
    gemm_f16<0,1><<<dim3(3,256),256,0,stream>>>(xh, wt+294912,   bv+l*DD, nullptr, vh, MROWS, DD, DD);

    betag_kernel<<<MROWS/4,256,0,stream>>>(x, Wb + (size_t)l*DD*HH, bb + l*HH,
                                           Wg + (size_t)l*DD*HH, bgp + l*HH,
                                           amask, beta, gbuf);
    knorm_kernel<<<MROWS*HH/8,256,0,stream>>>(kh);
    scan_kernel<<<BB*HH,64,0,stream>>>(qh, kh, vh, beta, gbuf, fl + l*HH, sl + l*HH);

    for (int c=0;c<2;c++){
      gemm_f16<0,0><<<dim3(3,128),256,0,stream>>>(qh + (size_t)c*16384*DD, wt+442368, bo+l*DD, f2, nullptr, 16384, DD, DD);
      add_ln_kernel<<<4096,256,0,stream>>>(x, xh, f2, alnw+l*DD, alnb+l*DD, c*16384);
    }
    for (int c=0;c<2;c++){
      gemm_f16<1,1><<<dim3(12,128),256,0,stream>>>(xh + (size_t)c*16384*DD, wt+589824,  b1+l*FFF, nullptr, hbf, 16384, FFF, DD);
      gemm_f16<0,0><<<dim3(3,128),256,0,stream>>>(hbf, wt+1179648, b2+l*DD, f2, nullptr, 16384, DD, FFF);
      add_ln_kernel<<<4096,256,0,stream>>>(x, xh, f2, flnw+l*DD, flnb+l*DD, c*16384);
    }
  }

  pool_kernel<<<BB,384,0,stream>>>(x, amask, out);
}

// Round 4
// 4376.758 us; speedup vs baseline: 3.3095x; 1.4193x over previous
//
#include <hip/hip_runtime.h>
#include <math.h>

#define DD 384
#define HH 12
#define DKK 32
#define LL 6
#define FFF 1536
#define BB 64
#define SS 512
#define MROWS (BB*SS)   // 32768
#define TB 32           // scan time-tile

typedef _Float16 f16;
typedef _Float16 half8 __attribute__((ext_vector_type(8)));
typedef float f32x4 __attribute__((ext_vector_type(4)));

__device__ __forceinline__ float sigmoidf_(float x){ return 1.0f/(1.0f+expf(-x)); }

__device__ __forceinline__ float h2f_lo(unsigned int u){
  union { unsigned short s; f16 h; } c; c.s = (unsigned short)(u & 0xffffu); return (float)c.h;
}
__device__ __forceinline__ float h2f_hi(unsigned int u){
  union { unsigned short s; f16 h; } c; c.s = (unsigned short)(u >> 16); return (float)c.h;
}

__device__ __forceinline__ void gl2lds16(const void* g, void* l){
  __builtin_amdgcn_global_load_lds((const __attribute__((address_space(1))) void*)g,
                                   (__attribute__((address_space(3))) void*)l, 16, 0, 0);
}

// ---------------- embedding + LN (writes fp32 x and f16 xh) ----------------
__global__ __launch_bounds__(256) void embed_ln_kernel(
    const int* __restrict__ ids, const float* __restrict__ we,
    const float* __restrict__ pe, const float* __restrict__ te,
    const float* __restrict__ w, const float* __restrict__ b,
    float* __restrict__ x, f16* __restrict__ xh)
{
  int wv = threadIdx.x >> 6, lane = threadIdx.x & 63;
  int row = blockIdx.x * 4 + wv;
  int s = row & (SS-1);
  int id = ids[row];
  const float* wep = we + (size_t)id * DD;
  const float* pep = pe + (size_t)s * DD;
  float vals[6]; float sum = 0.f;
  #pragma unroll
  for (int i=0;i<6;i++){ int d = lane + 64*i; vals[i] = wep[d] + pep[d] + te[d]; sum += vals[i]; }
  #pragma unroll
  for (int off=32; off>=1; off>>=1) sum += __shfl_xor(sum, off);
  float mean = sum * (1.0f/DD);
  float vs = 0.f;
  #pragma unroll
  for (int i=0;i<6;i++){ float dv = vals[i]-mean; vs += dv*dv; }
  #pragma unroll
  for (int off=32; off>=1; off>>=1) vs += __shfl_xor(vs, off);
  float inv = rsqrtf(vs*(1.0f/DD) + 1e-12f);
  float* xr = x + (size_t)row*DD;
  f16* xhr = xh + (size_t)row*DD;
  #pragma unroll
  for (int i=0;i<6;i++){ int d = lane + 64*i; float o = (vals[i]-mean)*inv*w[d] + b[d]; xr[d]=o; xhr[d]=(f16)o; }
}

// ---------------- x = LN(x + y); y is fp32 chunk starting at row0 ----------------
__global__ __launch_bounds__(256) void add_ln_kernel(
    float* __restrict__ x, f16* __restrict__ xh, const float* __restrict__ y,
    const float* __restrict__ w, const float* __restrict__ b, int row0)
{
  int wv = threadIdx.x >> 6, lane = threadIdx.x & 63;
  int row = row0 + blockIdx.x * 4 + wv;
  float* xr = x + (size_t)row*DD;
  f16* xhr = xh + (size_t)row*DD;
  const float* yr = y + (size_t)(blockIdx.x*4+wv)*DD;
  float vals[6]; float sum = 0.f;
  #pragma unroll
  for (int i=0;i<6;i++){ int d = lane + 64*i; vals[i] = xr[d] + yr[d]; sum += vals[i]; }
  #pragma unroll
  for (int off=32; off>=1; off>>=1) sum += __shfl_xor(sum, off);
  float mean = sum * (1.0f/DD);
  float vs = 0.f;
  #pragma unroll
  for (int i=0;i<6;i++){ float dv = vals[i]-mean; vs += dv*dv; }
  #pragma unroll
  for (int off=32; off>=1; off>>=1) vs += __shfl_xor(vs, off);
  float inv = rsqrtf(vs*(1.0f/DD) + 1e-12f);
  #pragma unroll
  for (int i=0;i<6;i++){ int d = lane + 64*i; float o = (vals[i]-mean)*inv*w[d] + b[d]; xr[d]=o; xhr[d]=(f16)o; }
}

// ---------------- weight transpose + f32->f16 (one layer) ----------------
__global__ __launch_bounds__(256) void wtrans_kernel(
  const float* __restrict__ Wq, const float* __restrict__ Wk, const float* __restrict__ Wv,
  const float* __restrict__ Wo, const float* __restrict__ W1, const float* __restrict__ W2,
  f16* __restrict__ Wt)
{
  __shared__ float T[32][33];
  int bidx = blockIdx.x;
  const float* src; f16* dst; int K, N, tile;
  if (bidx < 576){ int m = bidx/144; tile = bidx - m*144; K=384; N=384;
    src = (m==0)?Wq:(m==1)?Wk:(m==2)?Wv:Wo; dst = Wt + m*147456; }
  else if (bidx < 1152){ tile = bidx-576; K=384; N=1536; src=W1; dst=Wt+589824; }
  else { tile = bidx-1152; K=1536; N=384; src=W2; dst=Wt+1179648; }
  int tN = N>>5;
  int tk = tile / tN, tn = tile - tk*tN;
  int k0 = tk<<5, n0 = tn<<5;
  int r = threadIdx.x >> 3, c4 = (threadIdx.x & 7) << 2;
  float4 vv = *(const float4*)(src + (size_t)(k0+r)*N + n0 + c4);
  T[r][c4+0]=vv.x; T[r][c4+1]=vv.y; T[r][c4+2]=vv.z; T[r][c4+3]=vv.w;
  __syncthreads();
  f16* dp = dst + (size_t)(n0+r)*K + k0 + c4;
  #pragma unroll
  for (int j=0;j<4;j++) dp[j] = (f16)T[c4+j][r];
}

// ---------------- f16 MFMA GEMM: C = act(A @ BT^T + bias) ----------------
template<int ACT, int OUT16>
__global__ __launch_bounds__(256) void gemm_f16(
    const f16* __restrict__ A, const f16* __restrict__ BT,
    const float* __restrict__ bias, float* __restrict__ Cf, f16* __restrict__ Ch,
    int M, int N, int K)
{
  __shared__ __align__(16) f16 As[128*32];
  __shared__ __align__(16) f16 Bs[128*32];
  int tid = threadIdx.x, lane = tid & 63, wave = tid >> 6;
  int wm = wave >> 1, wn = wave & 1;
  int n0 = blockIdx.x * 128, m0 = blockIdx.y * 128;
  f32x4 acc[4][4] = {};
  int seg0 = wave*2048 + lane*16;
  int ar = lane & 15, kq = (lane >> 4) * 8;

  for (int k0=0; k0<K; k0+=32){
    #pragma unroll
    for (int i=0;i<2;i++){
      int seg = seg0 + i*1024;
      int e = seg >> 1; int row = e >> 5; int kk = e & 31;
      gl2lds16(A  + (size_t)(m0+row)*K + k0 + kk, (char*)As + seg);
      gl2lds16(BT + (size_t)(n0+row)*K + k0 + kk, (char*)Bs + seg);
    }
    __syncthreads();
    half8 af[4], bf[4];
    #pragma unroll
    for (int mi=0;mi<4;mi++) af[mi] = *(const half8*)&As[(wm*64 + mi*16 + ar)*32 + kq];
    #pragma unroll
    for (int ni=0;ni<4;ni++) bf[ni] = *(const half8*)&Bs[(wn*64 + ni*16 + ar)*32 + kq];
    #pragma unroll
    for (int mi=0;mi<4;mi++)
      #pragma unroll
      for (int ni=0;ni<4;ni++)
        acc[mi][ni] = __builtin_amdgcn_mfma_f32_16x16x32_f16(af[mi], bf[ni], acc[mi][ni], 0, 0, 0);
    __syncthreads();
  }
  int rb = (lane >> 4) * 4, cb = lane & 15;
  #pragma unroll
  for (int ni=0;ni<4;ni++){
    int cn = n0 + wn*64 + ni*16 + cb;
    float bz = bias[cn];
    #pragma unroll
    for (int mi=0;mi<4;mi++){
      int rm = m0 + wm*64 + mi*16 + rb;
      #pragma unroll
      for (int r=0;r<4;r++){
        float v = acc[mi][ni][r] + bz;
        if (ACT==1) v = 0.5f*v*(1.0f+erff(v*0.70710678118f));
        if (OUT16) Ch[(size_t)(rm+r)*N + cn] = (f16)v;
        else       Cf[(size_t)(rm+r)*N + cn] = v;
      }
    }
  }
}

// ---------------- beta/g projections ----------------
__global__ __launch_bounds__(256) void betag_kernel(
    const float* __restrict__ x, const float* __restrict__ Wb, const float* __restrict__ bb,
    const float* __restrict__ Wg, const float* __restrict__ bg,
    const int* __restrict__ mask, float* __restrict__ beta, float* __restrict__ g)
{
  __shared__ float Ws[384*25];
  for (int idx = threadIdx.x; idx < 384*12; idx += 256){
    int k = idx/12, j = idx - k*12;
    Ws[k*25+j]    = Wb[idx];
    Ws[k*25+12+j] = Wg[idx];
  }
  __syncthreads();
  int wv = threadIdx.x>>6, lane = threadIdx.x&63;
  int row = blockIdx.x*4 + wv;
  const float* xr = x + (size_t)row*DD;
  float accb[12], accg[12];
  #pragma unroll
  for (int j=0;j<12;j++){ accb[j]=0.f; accg[j]=0.f; }
  #pragma unroll
  for (int i=0;i<6;i++){
    int k = lane + 64*i;
    float xv = xr[k];
    const float* wr = &Ws[k*25];
    #pragma unroll
    for (int j=0;j<12;j++){ accb[j] += xv*wr[j]; accg[j] += xv*wr[12+j]; }
  }
  #pragma unroll
  for (int j=0;j<12;j++){
    #pragma unroll
    for (int off=32; off>=1; off>>=1){
      accb[j]+=__shfl_xor(accb[j],off);
      accg[j]+=__shfl_xor(accg[j],off);
    }
  }
  if (lane==0){
    float mk = (float)mask[row];
    #pragma unroll
    for (int j=0;j<12;j++){
      beta[(size_t)row*HH + j] = sigmoidf_(accb[j]+bb[j]) * mk;
      g[(size_t)row*HH + j]    = sigmoidf_(accg[j]+bg[j]);
    }
  }
}

// ---------------- DeltaNet dual-state scan, LDS time-tiled + pipelined ----------------
// One wave per (b,h). Lanes 0-31 fast state, 32-63 slow. Lane owns col d=lane&31.
// k-normalization fused into staging (quad-lane reduce), kept in f32 -> knorm kernel gone.
// q output written in-place (tile already staged to LDS before overwrite).
__global__ __launch_bounds__(64) void scan_kernel(
  f16* qo,
  const f16* __restrict__ kp, const f16* __restrict__ vp,
  const float* __restrict__ bp, const float* __restrict__ gp,
  const float* __restrict__ flp, const float* __restrict__ slp)
{
  __shared__ float Kf[2][TB][32];
  __shared__ float Qf[2][TB][32];
  __shared__ float Vf[2][TB][32];
  __shared__ float Bg[2][2][TB];
  int blk = blockIdx.x;
  int b = blk / HH, h = blk - b*HH;
  int lane = threadIdx.x;
  int col = lane & 31;
  float a = sigmoidf_((lane < 32) ? flp[h] : slp[h]);
  float S[32];
  #pragma unroll
  for (int j=0;j<32;j++) S[j]=0.f;
  size_t base = ((size_t)b*SS)*DD + (size_t)h*DKK;
  f16* qb = qo + base;                       // aliases out-stores; no restrict
  const f16* kb = kp + base;
  const f16* vb = vp + base;
  const float* bbp = bp + ((size_t)b*SS)*HH + h;
  const float* gbp = gp + ((size_t)b*SS)*HH + h;

  // staging lane map: round r covers steps r*16 + (lane>>2); part=(lane&3) -> 8 f16 elems
  int st0 = lane >> 2, part = lane & 3;
  uint4 kv[2], qv[2], vv[2]; float bgv;

  #define LOAD(T0) do {                                                        \
    _Pragma("unroll")                                                          \
    for (int r=0;r<2;r++){                                                     \
      int st = (T0) + r*16 + st0;                                              \
      size_t off = (size_t)st*DD + part*8;                                     \
      kv[r] = *(const uint4*)(kb + off);                                       \
      qv[r] = *(const uint4*)(qb + off);                                       \
      vv[r] = *(const uint4*)(vb + off);                                       \
    }                                                                          \
    int tb_ = (T0) + (lane & 31);                                              \
    bgv = (lane < 32) ? bbp[(size_t)tb_*HH] : gbp[(size_t)tb_*HH];             \
  } while(0)

  #define STORE(BUF) do {                                                      \
    _Pragma("unroll")                                                          \
    for (int r=0;r<2;r++){                                                     \
      int s = r*16 + st0;                                                      \
      float kf[8], qf[8], vf[8];                                               \
      kf[0]=h2f_lo(kv[r].x); kf[1]=h2f_hi(kv[r].x); kf[2]=h2f_lo(kv[r].y);     \
      kf[3]=h2f_hi(kv[r].y); kf[4]=h2f_lo(kv[r].z); kf[5]=h2f_hi(kv[r].z);     \
      kf[6]=h2f_lo(kv[r].w); kf[7]=h2f_hi(kv[r].w);                            \
      qf[0]=h2f_lo(qv[r].x); qf[1]=h2f_hi(qv[r].x); qf[2]=h2f_lo(qv[r].y);     \
      qf[3]=h2f_hi(qv[r].y); qf[4]=h2f_lo(qv[r].z); qf[5]=h2f_hi(qv[r].z);     \
      qf[6]=h2f_lo(qv[r].w); qf[7]=h2f_hi(qv[r].w);                            \
      vf[0]=h2f_lo(vv[r].x); vf[1]=h2f_hi(vv[r].x); vf[2]=h2f_lo(vv[r].y);     \
      vf[3]=h2f_hi(vv[r].y); vf[4]=h2f_lo(vv[r].z); vf[5]=h2f_hi(vv[r].z);     \
      vf[6]=h2f_lo(vv[r].w); vf[7]=h2f_hi(vv[r].w);                            \
      float ss = 0.f;                                                          \
      _Pragma("unroll")                                                        \
      for (int i=0;i<8;i++) ss += kf[i]*kf[i];                                 \
      ss += __shfl_xor(ss, 1); ss += __shfl_xor(ss, 2);                        \
      float sc = 1.0f/(sqrtf(ss)+1e-6f);                                       \
      float4 t;                                                                \
      t.x=kf[0]*sc; t.y=kf[1]*sc; t.z=kf[2]*sc; t.w=kf[3]*sc;                  \
      *(float4*)&Kf[BUF][s][part*8] = t;                                       \
      t.x=kf[4]*sc; t.y=kf[5]*sc; t.z=kf[6]*sc; t.w=kf[7]*sc;                  \
      *(float4*)&Kf[BUF][s][part*8+4] = t;                                     \
      t.x=qf[0]; t.y=qf[1]; t.z=qf[2]; t.w=qf[3];                              \
      *(float4*)&Qf[BUF][s][part*8] = t;                                       \
      t.x=qf[4]; t.y=qf[5]; t.z=qf[6]; t.w=qf[7];                              \
      *(float4*)&Qf[BUF][s][part*8+4] = t;                                     \
      t.x=vf[0]; t.y=vf[1]; t.z=vf[2]; t.w=vf[3];                              \
      *(float4*)&Vf[BUF][s][part*8] = t;                                       \
      t.x=vf[4]; t.y=vf[5]; t.z=vf[6]; t.w=vf[7];                              \
      *(float4*)&Vf[BUF][s][part*8+4] = t;                                     \
    }                                                                          \
    Bg[BUF][lane>>5][lane&31] = bgv;                                           \
  } while(0)

  LOAD(0);
  STORE(0);
  __syncthreads();

  for (int tile=0; tile<SS/TB; tile++){
    int buf = tile & 1;
    if (tile < SS/TB-1) LOAD((tile+1)*TB);     // prefetch next tile (latency hidden by compute)
    int t0 = tile*TB;
    #pragma unroll 1
    for (int s=0;s<TB;s++){
      float kt[32], qt[32];
      const float4* kr4 = (const float4*)&Kf[buf][s][0];
      const float4* qr4 = (const float4*)&Qf[buf][s][0];
      #pragma unroll
      for (int j=0;j<8;j++){
        float4 tk = kr4[j];
        kt[4*j]=tk.x; kt[4*j+1]=tk.y; kt[4*j+2]=tk.z; kt[4*j+3]=tk.w;
      }
      #pragma unroll
      for (int j=0;j<8;j++){
        float4 tq = qr4[j];
        qt[4*j]=tq.x; qt[4*j+1]=tq.y; qt[4*j+2]=tq.z; qt[4*j+3]=tq.w;
      }
      float vt = Vf[buf][s][col];
      float bt = Bg[buf][0][s];
      float gt = Bg[buf][1][s];
      float r0=0.f,r1=0.f,r2=0.f,r3=0.f;
      #pragma unroll
      for (int j=0;j<32;j+=4){
        r0 += S[j+0]*kt[j+0];
        r1 += S[j+1]*kt[j+1];
        r2 += S[j+2]*kt[j+2];
        r3 += S[j+3]*kt[j+3];
      }
      float rf = (r0+r1)+(r2+r3);
      float c = bt*(vt - rf);
      #pragma unroll
      for (int j=0;j<32;j++) S[j] = a*S[j] + c*kt[j];
      float o0=0.f,o1=0.f,o2=0.f,o3=0.f;
      #pragma unroll
      for (int j=0;j<32;j+=4){
        o0 += S[j+0]*qt[j+0];
        o1 += S[j+1]*qt[j+1];
        o2 += S[j+2]*qt[j+2];
        o3 += S[j+3]*qt[j+3];
      }
      float of = (o0+o1)+(o2+o3);
      float other = __shfl_xor(of, 32);
      if (lane < 32) qb[(size_t)(t0+s)*DD + col] = (f16)(gt*of + (1.0f-gt)*other);
    }
    if (tile < SS/TB-1) STORE(1-buf);
    __syncthreads();
  }
  #undef LOAD
  #undef STORE
}

// ---------------- masked mean-pool + L2 normalize ----------------
__global__ __launch_bounds__(384) void pool_kernel(
    const float* __restrict__ x, const int* __restrict__ mask, float* __restrict__ out)
{
  __shared__ float red[384];
  __shared__ float tot;
  int b = blockIdx.x, d = threadIdx.x;
  const float* xb = x + (size_t)b*SS*DD;
  const int* mb = mask + b*SS;
  float s=0.f, sm=0.f;
  for (int t=0;t<SS;t++){ float m=(float)mb[t]; s += xb[(size_t)t*DD+d]*m; sm += m; }
  float emb = s / fmaxf(sm, 1e-9f);
  red[d] = emb*emb;
  __syncthreads();
  for (int off=192; off>=3; off>>=1){
    if (d < off) red[d] += red[d+off];
    __syncthreads();
  }
  if (d==0) tot = red[0]+red[1]+red[2];
  __syncthreads();
  out[(size_t)b*DD + d] = emb * rsqrtf(tot);
}

extern "C" void kernel_launch(void* const* d_in, const int* in_sizes, int n_in,
                              void* d_out, int out_size, void* d_ws, size_t ws_size,
                              hipStream_t stream)
{
  const int*   ids  = (const int*)d_in[0];
  const int*   amask= (const int*)d_in[1];
  const float* we   = (const float*)d_in[2];
  const float* pe   = (const float*)d_in[3];
  const float* te   = (const float*)d_in[4];
  const float* elnw = (const float*)d_in[5];
  const float* elnb = (const float*)d_in[6];
  const float* Wq   = (const float*)d_in[7];
  const float* bq   = (const float*)d_in[8];
  const float* Wk   = (const float*)d_in[9];
  const float* bk   = (const float*)d_in[10];
  const float* Wv   = (const float*)d_in[11];
  const float* bv   = (const float*)d_in[12];
  const float* Wb   = (const float*)d_in[13];
  const float* bb   = (const float*)d_in[14];
  const float* Wg   = (const float*)d_in[15];
  const float* bgp  = (const float*)d_in[16];
  const float* Wo   = (const float*)d_in[17];
  const float* bo   = (const float*)d_in[18];
  const float* fl   = (const float*)d_in[19];
  const float* sl   = (const float*)d_in[20];
  const float* alnw = (const float*)d_in[21];
  const float* alnb = (const float*)d_in[22];
  const float* W1   = (const float*)d_in[23];
  const float* b1   = (const float*)d_in[24];
  const float* W2   = (const float*)d_in[25];
  const float* b2   = (const float*)d_in[26];
  const float* flnw = (const float*)d_in[27];
  const float* flnb = (const float*)d_in[28];
  float* out = (float*)d_out;
  float* w = (float*)d_ws;

  // workspace (float slots), total 44,924,928 floats = 179.7 MB
  float* x    = w;                      // 12,582,912 f
  f16*  xh   = (f16*)(w + 12582912);    // 12,582,912 h
  f16*  qh   = (f16*)(w + 18874368);    // 12,582,912 h  (attn out in-place)
  f16*  kh   = (f16*)(w + 25165824);    // 12,582,912 h
  f16*  vh   = (f16*)(w + 31457280);    // 12,582,912 h
  float* f2   = w + 37748736;           //  6,291,456 f  (chunk out; beta/g overlay)
  float* beta = f2;                     //    393,216 f
  float* gbuf = f2 + 393216;            //    393,216 f
  f16*  wt   = (f16*)(w + 44040192);    //  1,769,472 h
  f16*  hbf  = qh;                      // FFN hidden chunk 16384x1536 h

  embed_ln_kernel<<<MROWS/4, 256, 0, stream>>>(ids, we, pe, te, elnw, elnb, x, xh);

  for (int l=0;l<LL;l++){
    wtrans_kernel<<<1728,256,0,stream>>>(
        Wq + (size_t)l*147456, Wk + (size_t)l*147456, Wv + (size_t)l*147456,
        Wo + (size_t)l*147456, W1 + (size_t)l*589824, W2 + (size_t)l*589824, wt);

    gemm_f16<0,1><<<dim3(3,256),256,0,stream>>>(xh, wt,          bq+l*DD, nullptr, qh, MROWS, DD, DD);
    gemm_f16<0,1><<<dim3(3,256),256,0,stream>>>(xh, wt+147456,   bk+l*DD, nullptr, kh, MROWS, DD, DD);
    gemm_f16<0,1><<<dim3(3,256),256,0,stream>>>(xh, wt+294912,   bv+l*DD, nullptr, vh, MROWS, DD, DD);

    betag_kernel<<<MROWS/4,256,0,stream>>>(x, Wb + (size_t)l*DD*HH, bb + l*HH,
                                           Wg + (size_t)l*DD*HH, bgp + l*HH,
                                           amask, beta, gbuf);
    scan_kernel<<<BB*HH,64,0,stream>>>(qh, kh, vh, beta, gbuf, fl + l*HH, sl + l*HH);

    for (int c=0;c<2;c++){
      gemm_f16<0,0><<<dim3(3,128),256,0,stream>>>(qh + (size_t)c*16384*DD, wt+442368, bo+l*DD, f2, nullptr, 16384, DD, DD);
      add_ln_kernel<<<4096,256,0,stream>>>(x, xh, f2, alnw+l*DD, alnb+l*DD, c*16384);
    }
    for (int c=0;c<2;c++){
      gemm_f16<1,1><<<dim3(12,128),256,0,stream>>>(xh + (size_t)c*16384*DD, wt+589824,  b1+l*FFF, nullptr, hbf, 16384, FFF, DD);
      gemm_f16<0,0><<<dim3(3,128),256,0,stream>>>(hbf, wt+1179648, b2+l*DD, f2, nullptr, 16384, DD, FFF);
      add_ln_kernel<<<4096,256,0,stream>>>(x, xh, f2, flnw+l*DD, flnb+l*DD, c*16384);
    }
  }

  pool_kernel<<<BB,384,0,stream>>>(x, amask, out);
}

// Round 5
// 3713.008 us; speedup vs baseline: 3.9012x; 1.1788x over previous
//
#include <hip/hip_runtime.h>
#include <math.h>

#define DD 384
#define HH 12
#define DKK 32
#define LL 6
#define FFF 1536
#define BB 64
#define SS 512
#define MROWS (BB*SS)   // 32768
#define TB 32           // scan time-tile
#define LDX 1152        // qkv row stride

typedef _Float16 f16;
typedef _Float16 half8 __attribute__((ext_vector_type(8)));
typedef float f32x4 __attribute__((ext_vector_type(4)));
typedef float f32x2 __attribute__((ext_vector_type(2)));

__device__ __forceinline__ float sigmoidf_(float x){ return 1.0f/(1.0f+expf(-x)); }

__device__ __forceinline__ float h2f_lo(unsigned int u){
  union { unsigned short s; f16 h; } c; c.s = (unsigned short)(u & 0xffffu); return (float)c.h;
}
__device__ __forceinline__ float h2f_hi(unsigned int u){
  union { unsigned short s; f16 h; } c; c.s = (unsigned short)(u >> 16); return (float)c.h;
}

__device__ __forceinline__ void gl2lds16(const void* g, void* l){
  __builtin_amdgcn_global_load_lds((const __attribute__((address_space(1))) void*)g,
                                   (__attribute__((address_space(3))) void*)l, 16, 0, 0);
}

// ---------------- embedding + LN (writes fp32 x and f16 xh) ----------------
__global__ __launch_bounds__(256) void embed_ln_kernel(
    const int* __restrict__ ids, const float* __restrict__ we,
    const float* __restrict__ pe, const float* __restrict__ te,
    const float* __restrict__ w, const float* __restrict__ b,
    float* __restrict__ x, f16* __restrict__ xh)
{
  int wv = threadIdx.x >> 6, lane = threadIdx.x & 63;
  int row = blockIdx.x * 4 + wv;
  int s = row & (SS-1);
  int id = ids[row];
  const float* wep = we + (size_t)id * DD;
  const float* pep = pe + (size_t)s * DD;
  float vals[6]; float sum = 0.f;
  #pragma unroll
  for (int i=0;i<6;i++){ int d = lane + 64*i; vals[i] = wep[d] + pep[d] + te[d]; sum += vals[i]; }
  #pragma unroll
  for (int off=32; off>=1; off>>=1) sum += __shfl_xor(sum, off);
  float mean = sum * (1.0f/DD);
  float vs = 0.f;
  #pragma unroll
  for (int i=0;i<6;i++){ float dv = vals[i]-mean; vs += dv*dv; }
  #pragma unroll
  for (int off=32; off>=1; off>>=1) vs += __shfl_xor(vs, off);
  float inv = rsqrtf(vs*(1.0f/DD) + 1e-12f);
  float* xr = x + (size_t)row*DD;
  f16* xhr = xh + (size_t)row*DD;
  #pragma unroll
  for (int i=0;i<6;i++){ int d = lane + 64*i; float o = (vals[i]-mean)*inv*w[d] + b[d]; xr[d]=o; xhr[d]=(f16)o; }
}

// ---------------- x = LN(x + y); y is fp32 chunk starting at row0 ----------------
__global__ __launch_bounds__(256) void add_ln_kernel(
    float* __restrict__ x, f16* __restrict__ xh, const float* __restrict__ y,
    const float* __restrict__ w, const float* __restrict__ b, int row0)
{
  int wv = threadIdx.x >> 6, lane = threadIdx.x & 63;
  int row = row0 + blockIdx.x * 4 + wv;
  float* xr = x + (size_t)row*DD;
  f16* xhr = xh + (size_t)row*DD;
  const float* yr = y + (size_t)(blockIdx.x*4+wv)*DD;
  float vals[6]; float sum = 0.f;
  #pragma unroll
  for (int i=0;i<6;i++){ int d = lane + 64*i; vals[i] = xr[d] + yr[d]; sum += vals[i]; }
  #pragma unroll
  for (int off=32; off>=1; off>>=1) sum += __shfl_xor(sum, off);
  float mean = sum * (1.0f/DD);
  float vs = 0.f;
  #pragma unroll
  for (int i=0;i<6;i++){ float dv = vals[i]-mean; vs += dv*dv; }
  #pragma unroll
  for (int off=32; off>=1; off>>=1) vs += __shfl_xor(vs, off);
  float inv = rsqrtf(vs*(1.0f/DD) + 1e-12f);
  #pragma unroll
  for (int i=0;i<6;i++){ int d = lane + 64*i; float o = (vals[i]-mean)*inv*w[d] + b[d]; xr[d]=o; xhr[d]=(f16)o; }
}

// ---------------- bias pack: [bq;bk;bv] per layer -> 1152 each ----------------
__global__ __launch_bounds__(256) void biaspack_kernel(
    const float* __restrict__ bq, const float* __restrict__ bk, const float* __restrict__ bv,
    float* __restrict__ dst)
{
  int i = blockIdx.x*256 + threadIdx.x;   // 6912 total
  if (i >= LL*LDX) return;
  int l = i / LDX, r = i - l*LDX;
  float v;
  if (r < 384) v = bq[l*DD + r];
  else if (r < 768) v = bk[l*DD + r-384];
  else v = bv[l*DD + r-768];
  dst[i] = v;
}

// ---------------- weight transpose + f32->f16 (one layer) ----------------
__global__ __launch_bounds__(256) void wtrans_kernel(
  const float* __restrict__ Wq, const float* __restrict__ Wk, const float* __restrict__ Wv,
  const float* __restrict__ Wo, const float* __restrict__ W1, const float* __restrict__ W2,
  f16* __restrict__ Wt)
{
  __shared__ float T[32][33];
  int bidx = blockIdx.x;
  const float* src; f16* dst; int K, N, tile;
  if (bidx < 576){ int m = bidx/144; tile = bidx - m*144; K=384; N=384;
    src = (m==0)?Wq:(m==1)?Wk:(m==2)?Wv:Wo; dst = Wt + m*147456; }
  else if (bidx < 1152){ tile = bidx-576; K=384; N=1536; src=W1; dst=Wt+589824; }
  else { tile = bidx-1152; K=1536; N=384; src=W2; dst=Wt+1179648; }
  int tN = N>>5;
  int tk = tile / tN, tn = tile - tk*tN;
  int k0 = tk<<5, n0 = tn<<5;
  int r = threadIdx.x >> 3, c4 = (threadIdx.x & 7) << 2;
  float4 vv = *(const float4*)(src + (size_t)(k0+r)*N + n0 + c4);
  T[r][c4+0]=vv.x; T[r][c4+1]=vv.y; T[r][c4+2]=vv.z; T[r][c4+3]=vv.w;
  __syncthreads();
  f16* dp = dst + (size_t)(n0+r)*K + k0 + c4;
  #pragma unroll
  for (int j=0;j<4;j++) dp[j] = (f16)T[c4+j][r];
}

// ---------------- f16 MFMA GEMM: C = act(A @ BT^T + bias), strided A/C ----------------
template<int ACT, int OUT16>
__global__ __launch_bounds__(256) void gemm_f16(
    const f16* __restrict__ A, const f16* __restrict__ BT,
    const float* __restrict__ bias, float* __restrict__ Cf, f16* __restrict__ Ch,
    int M, int N, int K, int lda, int ldc)
{
  __shared__ __align__(16) f16 As[128*32];
  __shared__ __align__(16) f16 Bs[128*32];
  int tid = threadIdx.x, lane = tid & 63, wave = tid >> 6;
  int wm = wave >> 1, wn = wave & 1;
  int n0 = blockIdx.x * 128, m0 = blockIdx.y * 128;
  f32x4 acc[4][4] = {};
  int seg0 = wave*2048 + lane*16;
  int ar = lane & 15, kq = (lane >> 4) * 8;

  for (int k0=0; k0<K; k0+=32){
    #pragma unroll
    for (int i=0;i<2;i++){
      int seg = seg0 + i*1024;
      int e = seg >> 1; int row = e >> 5; int kk = e & 31;
      gl2lds16(A  + (size_t)(m0+row)*lda + k0 + kk, (char*)As + seg);
      gl2lds16(BT + (size_t)(n0+row)*K   + k0 + kk, (char*)Bs + seg);
    }
    __syncthreads();
    half8 af[4], bf[4];
    #pragma unroll
    for (int mi=0;mi<4;mi++) af[mi] = *(const half8*)&As[(wm*64 + mi*16 + ar)*32 + kq];
    #pragma unroll
    for (int ni=0;ni<4;ni++) bf[ni] = *(const half8*)&Bs[(wn*64 + ni*16 + ar)*32 + kq];
    #pragma unroll
    for (int mi=0;mi<4;mi++)
      #pragma unroll
      for (int ni=0;ni<4;ni++)
        acc[mi][ni] = __builtin_amdgcn_mfma_f32_16x16x32_f16(af[mi], bf[ni], acc[mi][ni], 0, 0, 0);
    __syncthreads();
  }
  int rb = (lane >> 4) * 4, cb = lane & 15;
  #pragma unroll
  for (int ni=0;ni<4;ni++){
    int cn = n0 + wn*64 + ni*16 + cb;
    float bz = bias[cn];
    #pragma unroll
    for (int mi=0;mi<4;mi++){
      int rm = m0 + wm*64 + mi*16 + rb;
      #pragma unroll
      for (int r=0;r<4;r++){
        float v = acc[mi][ni][r] + bz;
        if (ACT==1) v = 0.5f*v*(1.0f+erff(v*0.70710678118f));
        if (OUT16) Ch[(size_t)(rm+r)*ldc + cn] = (f16)v;
        else       Cf[(size_t)(rm+r)*ldc + cn] = v;
      }
    }
  }
}

// ---------------- beta/g projections ----------------
__global__ __launch_bounds__(256) void betag_kernel(
    const float* __restrict__ x, const float* __restrict__ Wb, const float* __restrict__ bb,
    const float* __restrict__ Wg, const float* __restrict__ bg,
    const int* __restrict__ mask, float* __restrict__ beta, float* __restrict__ g)
{
  __shared__ float Ws[384*25];
  for (int idx = threadIdx.x; idx < 384*12; idx += 256){
    int k = idx/12, j = idx - k*12;
    Ws[k*25+j]    = Wb[idx];
    Ws[k*25+12+j] = Wg[idx];
  }
  __syncthreads();
  int wv = threadIdx.x>>6, lane = threadIdx.x&63;
  int row = blockIdx.x*4 + wv;
  const float* xr = x + (size_t)row*DD;
  float accb[12], accg[12];
  #pragma unroll
  for (int j=0;j<12;j++){ accb[j]=0.f; accg[j]=0.f; }
  #pragma unroll
  for (int i=0;i<6;i++){
    int k = lane + 64*i;
    float xv = xr[k];
    const float* wr = &Ws[k*25];
    #pragma unroll
    for (int j=0;j<12;j++){ accb[j] += xv*wr[j]; accg[j] += xv*wr[12+j]; }
  }
  #pragma unroll
  for (int j=0;j<12;j++){
    #pragma unroll
    for (int off=32; off>=1; off>>=1){
      accb[j]+=__shfl_xor(accb[j],off);
      accg[j]+=__shfl_xor(accg[j],off);
    }
  }
  if (lane==0){
    float mk = (float)mask[row];
    #pragma unroll
    for (int j=0;j<12;j++){
      beta[(size_t)row*HH + j] = sigmoidf_(accb[j]+bb[j]) * mk;
      g[(size_t)row*HH + j]    = sigmoidf_(accg[j]+bg[j]);
    }
  }
}

// ---------------- DeltaNet dual-state scan: LDS tiles + 2-step register pipeline ----------------
// One wave per (b,h). Lanes 0-31 fast, 32-63 slow; lane owns col=lane&31.
// qkv layout [row][1152]: q[0:384] k[384:768] v[768:1152]; out written in-place over q.
// k-normalization fused at staging. Packed f32x2 math for v_pk_fma_f32.
__global__ __launch_bounds__(64) void scan_kernel(
  f16* qkv,
  const float* __restrict__ bp, const float* __restrict__ gp,
  const float* __restrict__ flp, const float* __restrict__ slp)
{
  __shared__ float Kf[2][TB][32];
  __shared__ float Qf[2][TB][32];
  __shared__ float Vf[2][TB][32];
  __shared__ float Bg[2][2][TB];
  int blk = blockIdx.x;
  int b = blk / HH, h = blk - b*HH;
  int lane = threadIdx.x;
  int col = lane & 31;
  float a = sigmoidf_((lane < 32) ? flp[h] : slp[h]);
  f32x2 a2 = {a, a};
  f32x2 S2[16];
  #pragma unroll
  for (int j=0;j<16;j++) S2[j] = (f32x2){0.f,0.f};
  size_t base = ((size_t)b*SS)*LDX + (size_t)h*DKK;
  f16* qb = qkv + base;                       // in-place out; aliases loads
  const f16* kb = qkv + base + 384;
  const f16* vb = qkv + base + 768;
  const float* bbp = bp + ((size_t)b*SS)*HH + h;
  const float* gbp = gp + ((size_t)b*SS)*HH + h;

  int st0 = lane >> 2, part = lane & 3;
  uint4 kv[2], qv[2], vv[2]; float bgv;

  #define LOADG(T0) do {                                                       \
    _Pragma("unroll")                                                          \
    for (int r=0;r<2;r++){                                                     \
      int st = (T0) + r*16 + st0;                                              \
      size_t off = (size_t)st*LDX + part*8;                                    \
      kv[r] = *(const uint4*)(kb + off);                                       \
      qv[r] = *(const uint4*)(qb + off);                                       \
      vv[r] = *(const uint4*)(vb + off);                                       \
    }                                                                          \
    int tb_ = (T0) + (lane & 31);                                              \
    bgv = (lane < 32) ? bbp[(size_t)tb_*HH] : gbp[(size_t)tb_*HH];             \
  } while(0)

  #define STAGE(BUF) do {                                                      \
    _Pragma("unroll")                                                          \
    for (int r=0;r<2;r++){                                                     \
      int s = r*16 + st0;                                                      \
      float kf[8], qf[8], vf[8];                                               \
      kf[0]=h2f_lo(kv[r].x); kf[1]=h2f_hi(kv[r].x); kf[2]=h2f_lo(kv[r].y);     \
      kf[3]=h2f_hi(kv[r].y); kf[4]=h2f_lo(kv[r].z); kf[5]=h2f_hi(kv[r].z);     \
      kf[6]=h2f_lo(kv[r].w); kf[7]=h2f_hi(kv[r].w);                            \
      qf[0]=h2f_lo(qv[r].x); qf[1]=h2f_hi(qv[r].x); qf[2]=h2f_lo(qv[r].y);     \
      qf[3]=h2f_hi(qv[r].y); qf[4]=h2f_lo(qv[r].z); qf[5]=h2f_hi(qv[r].z);     \
      qf[6]=h2f_lo(qv[r].w); qf[7]=h2f_hi(qv[r].w);                            \
      vf[0]=h2f_lo(vv[r].x); vf[1]=h2f_hi(vv[r].x); vf[2]=h2f_lo(vv[r].y);     \
      vf[3]=h2f_hi(vv[r].y); vf[4]=h2f_lo(vv[r].z); vf[5]=h2f_hi(vv[r].z);     \
      vf[6]=h2f_lo(vv[r].w); vf[7]=h2f_hi(vv[r].w);                            \
      float ss = 0.f;                                                          \
      _Pragma("unroll")                                                        \
      for (int i=0;i<8;i++) ss += kf[i]*kf[i];                                 \
      ss += __shfl_xor(ss, 1); ss += __shfl_xor(ss, 2);                        \
      float sc = 1.0f/(sqrtf(ss)+1e-6f);                                       \
      float4 t;                                                                \
      t.x=kf[0]*sc; t.y=kf[1]*sc; t.z=kf[2]*sc; t.w=kf[3]*sc;                  \
      *(float4*)&Kf[BUF][s][part*8] = t;                                       \
      t.x=kf[4]*sc; t.y=kf[5]*sc; t.z=kf[6]*sc; t.w=kf[7]*sc;                  \
      *(float4*)&Kf[BUF][s][part*8+4] = t;                                     \
      t.x=qf[0]; t.y=qf[1]; t.z=qf[2]; t.w=qf[3];                              \
      *(float4*)&Qf[BUF][s][part*8] = t;                                       \
      t.x=qf[4]; t.y=qf[5]; t.z=qf[6]; t.w=qf[7];                              \
      *(float4*)&Qf[BUF][s][part*8+4] = t;                                     \
      t.x=vf[0]; t.y=vf[1]; t.z=vf[2]; t.w=vf[3];                              \
      *(float4*)&Vf[BUF][s][part*8] = t;                                       \
      t.x=vf[4]; t.y=vf[5]; t.z=vf[6]; t.w=vf[7];                              \
      *(float4*)&Vf[BUF][s][part*8+4] = t;                                     \
    }                                                                          \
    Bg[BUF][lane>>5][lane&31] = bgv;                                           \
  } while(0)

  // load step data from LDS into regs
  #define LDSTEP(BUF,S,KR,QR,VT,BT,GT) do {                                    \
    const float4* k4_ = (const float4*)&Kf[BUF][S][0];                         \
    const float4* q4_ = (const float4*)&Qf[BUF][S][0];                         \
    _Pragma("unroll")                                                          \
    for (int j=0;j<8;j++){ KR[j]=k4_[j]; QR[j]=q4_[j]; }                       \
    VT = Vf[BUF][S][col]; BT = Bg[BUF][0][S]; GT = Bg[BUF][1][S];              \
  } while(0)

  #define STEP(KR,QR,VT,BT,GT,T) do {                                         \
    const f32x2* k2_ = (const f32x2*)KR;                                       \
    const f32x2* q2_ = (const f32x2*)QR;                                       \
    f32x2 rA={0.f,0.f},rB={0.f,0.f},rC={0.f,0.f},rD={0.f,0.f};                 \
    _Pragma("unroll")                                                          \
    for (int j=0;j<16;j+=4){                                                   \
      rA += S2[j+0]*k2_[j+0]; rB += S2[j+1]*k2_[j+1];                          \
      rC += S2[j+2]*k2_[j+2]; rD += S2[j+3]*k2_[j+3]; }                        \
    f32x2 rr = (rA+rB)+(rC+rD);                                                \
    float rf = rr.x + rr.y;                                                    \
    float c_ = (BT)*((VT) - rf);                                               \
    f32x2 c2 = {c_, c_};                                                       \
    _Pragma("unroll")                                                          \
    for (int j=0;j<16;j++) S2[j] = a2*S2[j] + c2*k2_[j];                       \
    f32x2 oA={0.f,0.f},oB={0.f,0.f},oC={0.f,0.f},oD={0.f,0.f};                 \
    _Pragma("unroll")                                                          \
    for (int j=0;j<16;j+=4){                                                   \
      oA += S2[j+0]*q2_[j+0]; oB += S2[j+1]*q2_[j+1];                          \
      oC += S2[j+2]*q2_[j+2]; oD += S2[j+3]*q2_[j+3]; }                        \
    f32x2 oo = (oA+oB)+(oC+oD);                                                \
    float of = oo.x + oo.y;                                                    \
    float other = __shfl_xor(of, 32);                                          \
    if (lane < 32) qb[(size_t)(T)*LDX + col] = (f16)((GT)*of + (1.0f-(GT))*other); \
  } while(0)

  LOADG(0);
  STAGE(0);
  __syncthreads();

  float4 kA[8], qA[8], kB[8], qB[8];
  float vA, bA, gA, vB, bB, gB;

  for (int tile=0; tile<SS/TB; tile++){
    int buf = tile & 1;
    if (tile < SS/TB-1) LOADG((tile+1)*TB);   // global prefetch of next tile
    int t0 = tile*TB;
    LDSTEP(buf, 0, kA, qA, vA, bA, gA);
    #pragma unroll
    for (int s=0; s<TB; s+=2){
      if (s+1 < TB) LDSTEP(buf, s+1, kB, qB, vB, bB, gB);
      STEP(kA, qA, vA, bA, gA, t0+s);
      if (s+2 < TB) LDSTEP(buf, s+2, kA, qA, vA, bA, gA);
      STEP(kB, qB, vB, bB, gB, t0+s+1);
    }
    if (tile < SS/TB-1) STAGE(1-buf);
    __syncthreads();
  }
  #undef LOADG
  #undef STAGE
  #undef LDSTEP
  #undef STEP
}

// ---------------- masked mean-pool + L2 normalize ----------------
__global__ __launch_bounds__(384) void pool_kernel(
    const float* __restrict__ x, const int* __restrict__ mask, float* __restrict__ out)
{
  __shared__ float red[384];
  __shared__ float tot;
  int b = blockIdx.x, d = threadIdx.x;
  const float* xb = x + (size_t)b*SS*DD;
  const int* mb = mask + b*SS;
  float s=0.f, sm=0.f;
  for (int t=0;t<SS;t++){ float m=(float)mb[t]; s += xb[(size_t)t*DD+d]*m; sm += m; }
  float emb = s / fmaxf(sm, 1e-9f);
  red[d] = emb*emb;
  __syncthreads();
  for (int off=192; off>=3; off>>=1){
    if (d < off) red[d] += red[d+off];
    __syncthreads();
  }
  if (d==0) tot = red[0]+red[1]+red[2];
  __syncthreads();
  out[(size_t)b*DD + d] = emb * rsqrtf(tot);
}

extern "C" void kernel_launch(void* const* d_in, const int* in_sizes, int n_in,
                              void* d_out, int out_size, void* d_ws, size_t ws_size,
                              hipStream_t stream)
{
  const int*   ids  = (const int*)d_in[0];
  const int*   amask= (const int*)d_in[1];
  const float* we   = (const float*)d_in[2];
  const float* pe   = (const float*)d_in[3];
  const float* te   = (const float*)d_in[4];
  const float* elnw = (const float*)d_in[5];
  const float* elnb = (const float*)d_in[6];
  const float* Wq   = (const float*)d_in[7];
  const float* bq   = (const float*)d_in[8];
  const float* Wk   = (const float*)d_in[9];
  const float* bk   = (const float*)d_in[10];
  const float* Wv   = (const float*)d_in[11];
  const float* bv   = (const float*)d_in[12];
  const float* Wb   = (const float*)d_in[13];
  const float* bb   = (const float*)d_in[14];
  const float* Wg   = (const float*)d_in[15];
  const float* bgp  = (const float*)d_in[16];
  const float* Wo   = (const float*)d_in[17];
  const float* bo   = (const float*)d_in[18];
  const float* fl   = (const float*)d_in[19];
  const float* sl   = (const float*)d_in[20];
  const float* alnw = (const float*)d_in[21];
  const float* alnb = (const float*)d_in[22];
  const float* W1   = (const float*)d_in[23];
  const float* b1   = (const float*)d_in[24];
  const float* W2   = (const float*)d_in[25];
  const float* b2   = (const float*)d_in[26];
  const float* flnw = (const float*)d_in[27];
  const float* flnb = (const float*)d_in[28];
  float* out = (float*)d_out;
  float* w = (float*)d_ws;

  // workspace (float slots)
  float* x    = w;                      // 12,582,912 f
  f16*  xh   = (f16*)(w + 12582912);    // 12,582,912 h (6,291,456 f)
  f16*  qkvh = (f16*)(w + 18874368);    // 37,748,736 h (18,874,368 f)  [row][1152]
  float* f2   = w + 37748736;           //  6,291,456 f (chunk out; beta/g overlay)
  float* beta = f2;                     //    393,216 f
  float* gbuf = f2 + 393216;            //    393,216 f
  f16*  wt   = (f16*)(w + 44040192);    //  1,769,472 h (884,736 f)
  float* bqkv = w + 44924928;           //      6,912 f
  f16*  hbf  = qkvh;                    // FFN hidden chunk 16384x1536 h (25.2M h) overlays qkv
  // total 44,931,840 f = 179.7 MB

  embed_ln_kernel<<<MROWS/4, 256, 0, stream>>>(ids, we, pe, te, elnw, elnb, x, xh);
  biaspack_kernel<<<27,256,0,stream>>>(bq, bk, bv, bqkv);

  for (int l=0;l<LL;l++){
    wtrans_kernel<<<1728,256,0,stream>>>(
        Wq + (size_t)l*147456, Wk + (size_t)l*147456, Wv + (size_t)l*147456,
        Wo + (size_t)l*147456, W1 + (size_t)l*589824, W2 + (size_t)l*589824, wt);

    // fused QKV: [32768 x 1152] = xh @ [Wq|Wk|Wv]^T
    gemm_f16<0,1><<<dim3(9,256),256,0,stream>>>(xh, wt, bqkv + l*LDX, nullptr, qkvh,
                                                MROWS, LDX, DD, DD, LDX);

    betag_kernel<<<MROWS/4,256,0,stream>>>(x, Wb + (size_t)l*DD*HH, bb + l*HH,
                                           Wg + (size_t)l*DD*HH, bgp + l*HH,
                                           amask, beta, gbuf);
    scan_kernel<<<BB*HH,64,0,stream>>>(qkvh, beta, gbuf, fl + l*HH, sl + l*HH);

    // o-proj: A = attn-out = qkv[:,0:384] (lda=1152)
    for (int c=0;c<2;c++){
      gemm_f16<0,0><<<dim3(3,128),256,0,stream>>>(qkvh + (size_t)c*16384*LDX, wt+442368,
                                                  bo+l*DD, f2, nullptr, 16384, DD, DD, LDX, DD);
      add_ln_kernel<<<4096,256,0,stream>>>(x, xh, f2, alnw+l*DD, alnb+l*DD, c*16384);
    }
    // FFN (qkv dead -> hidden overlays it)
    for (int c=0;c<2;c++){
      gemm_f16<1,1><<<dim3(12,128),256,0,stream>>>(xh + (size_t)c*16384*DD, wt+589824,
                                                   b1+l*FFF, nullptr, hbf, 16384, FFF, DD, DD, FFF);
      gemm_f16<0,0><<<dim3(3,128),256,0,stream>>>(hbf, wt+1179648, b2+l*DD, f2, nullptr,
                                                  16384, DD, FFF, FFF, DD);
      add_ln_kernel<<<4096,256,0,stream>>>(x, xh, f2, flnw+l*DD, flnb+l*DD, c*16384);
    }
  }

  pool_kernel<<<BB,384,0,stream>>>(x, amask, out);
}

// Round 6
// 3644.705 us; speedup vs baseline: 3.9743x; 1.0187x over previous
//
#include <hip/hip_runtime.h>
#include <math.h>

#define DD 384
#define HH 12
#define DKK 32
#define LL 6
#define FFF 1536
#define BB 64
#define SS 512
#define MROWS (BB*SS)   // 32768
#define TB 32           // scan time-tile
#define LDX 1152        // qkv row stride

typedef _Float16 f16;
typedef _Float16 half8 __attribute__((ext_vector_type(8)));
typedef float f32x4 __attribute__((ext_vector_type(4)));
typedef float f32x2 __attribute__((ext_vector_type(2)));

__device__ __forceinline__ float sigmoidf_(float x){ return 1.0f/(1.0f+expf(-x)); }

__device__ __forceinline__ float h2f_lo(unsigned int u){
  union { unsigned short s; f16 h; } c; c.s = (unsigned short)(u & 0xffffu); return (float)c.h;
}
__device__ __forceinline__ float h2f_hi(unsigned int u){
  union { unsigned short s; f16 h; } c; c.s = (unsigned short)(u >> 16); return (float)c.h;
}

__device__ __forceinline__ void gl2lds16(const void* g, void* l){
  __builtin_amdgcn_global_load_lds((const __attribute__((address_space(1))) void*)g,
                                   (__attribute__((address_space(3))) void*)l, 16, 0, 0);
}

// ---------------- embedding + LN (writes fp32 x and f16 xh) ----------------
__global__ __launch_bounds__(256) void embed_ln_kernel(
    const int* __restrict__ ids, const float* __restrict__ we,
    const float* __restrict__ pe, const float* __restrict__ te,
    const float* __restrict__ w, const float* __restrict__ b,
    float* __restrict__ x, f16* __restrict__ xh)
{
  int wv = threadIdx.x >> 6, lane = threadIdx.x & 63;
  int row = blockIdx.x * 4 + wv;
  int s = row & (SS-1);
  int id = ids[row];
  const float* wep = we + (size_t)id * DD;
  const float* pep = pe + (size_t)s * DD;
  float vals[6]; float sum = 0.f;
  #pragma unroll
  for (int i=0;i<6;i++){ int d = lane + 64*i; vals[i] = wep[d] + pep[d] + te[d]; sum += vals[i]; }
  #pragma unroll
  for (int off=32; off>=1; off>>=1) sum += __shfl_xor(sum, off);
  float mean = sum * (1.0f/DD);
  float vs = 0.f;
  #pragma unroll
  for (int i=0;i<6;i++){ float dv = vals[i]-mean; vs += dv*dv; }
  #pragma unroll
  for (int off=32; off>=1; off>>=1) vs += __shfl_xor(vs, off);
  float inv = rsqrtf(vs*(1.0f/DD) + 1e-12f);
  float* xr = x + (size_t)row*DD;
  f16* xhr = xh + (size_t)row*DD;
  #pragma unroll
  for (int i=0;i<6;i++){ int d = lane + 64*i; float o = (vals[i]-mean)*inv*w[d] + b[d]; xr[d]=o; xhr[d]=(f16)o; }
}

// ---------------- x = LN(x + y); y is fp32 chunk starting at row0 ----------------
__global__ __launch_bounds__(256) void add_ln_kernel(
    float* __restrict__ x, f16* __restrict__ xh, const float* __restrict__ y,
    const float* __restrict__ w, const float* __restrict__ b, int row0)
{
  int wv = threadIdx.x >> 6, lane = threadIdx.x & 63;
  int row = row0 + blockIdx.x * 4 + wv;
  float* xr = x + (size_t)row*DD;
  f16* xhr = xh + (size_t)row*DD;
  const float* yr = y + (size_t)(blockIdx.x*4+wv)*DD;
  float vals[6]; float sum = 0.f;
  #pragma unroll
  for (int i=0;i<6;i++){ int d = lane + 64*i; vals[i] = xr[d] + yr[d]; sum += vals[i]; }
  #pragma unroll
  for (int off=32; off>=1; off>>=1) sum += __shfl_xor(sum, off);
  float mean = sum * (1.0f/DD);
  float vs = 0.f;
  #pragma unroll
  for (int i=0;i<6;i++){ float dv = vals[i]-mean; vs += dv*dv; }
  #pragma unroll
  for (int off=32; off>=1; off>>=1) vs += __shfl_xor(vs, off);
  float inv = rsqrtf(vs*(1.0f/DD) + 1e-12f);
  #pragma unroll
  for (int i=0;i<6;i++){ int d = lane + 64*i; float o = (vals[i]-mean)*inv*w[d] + b[d]; xr[d]=o; xhr[d]=(f16)o; }
}

// ---------------- bias pack: [bq;bk;bv] per layer -> 1152 each ----------------
__global__ __launch_bounds__(256) void biaspack_kernel(
    const float* __restrict__ bq, const float* __restrict__ bk, const float* __restrict__ bv,
    float* __restrict__ dst)
{
  int i = blockIdx.x*256 + threadIdx.x;   // 6912 total
  if (i >= LL*LDX) return;
  int l = i / LDX, r = i - l*LDX;
  float v;
  if (r < 384) v = bq[l*DD + r];
  else if (r < 768) v = bk[l*DD + r-384];
  else v = bv[l*DD + r-768];
  dst[i] = v;
}

// ---------------- weight transpose + f32->f16 (one layer) ----------------
__global__ __launch_bounds__(256) void wtrans_kernel(
  const float* __restrict__ Wq, const float* __restrict__ Wk, const float* __restrict__ Wv,
  const float* __restrict__ Wo, const float* __restrict__ W1, const float* __restrict__ W2,
  f16* __restrict__ Wt)
{
  __shared__ float T[32][33];
  int bidx = blockIdx.x;
  const float* src; f16* dst; int K, N, tile;
  if (bidx < 576){ int m = bidx/144; tile = bidx - m*144; K=384; N=384;
    src = (m==0)?Wq:(m==1)?Wk:(m==2)?Wv:Wo; dst = Wt + m*147456; }
  else if (bidx < 1152){ tile = bidx-576; K=384; N=1536; src=W1; dst=Wt+589824; }
  else { tile = bidx-1152; K=1536; N=384; src=W2; dst=Wt+1179648; }
  int tN = N>>5;
  int tk = tile / tN, tn = tile - tk*tN;
  int k0 = tk<<5, n0 = tn<<5;
  int r = threadIdx.x >> 3, c4 = (threadIdx.x & 7) << 2;
  float4 vv = *(const float4*)(src + (size_t)(k0+r)*N + n0 + c4);
  T[r][c4+0]=vv.x; T[r][c4+1]=vv.y; T[r][c4+2]=vv.z; T[r][c4+3]=vv.w;
  __syncthreads();
  f16* dp = dst + (size_t)(n0+r)*K + k0 + c4;
  #pragma unroll
  for (int j=0;j<4;j++) dp[j] = (f16)T[c4+j][r];
}

// ---------------- f16 MFMA GEMM: C = act(A @ BT^T + bias), strided A/C ----------------
template<int ACT, int OUT16>
__global__ __launch_bounds__(256) void gemm_f16(
    const f16* __restrict__ A, const f16* __restrict__ BT,
    const float* __restrict__ bias, float* __restrict__ Cf, f16* __restrict__ Ch,
    int M, int N, int K, int lda, int ldc)
{
  __shared__ __align__(16) f16 As[128*32];
  __shared__ __align__(16) f16 Bs[128*32];
  int tid = threadIdx.x, lane = tid & 63, wave = tid >> 6;
  int wm = wave >> 1, wn = wave & 1;
  int n0 = blockIdx.x * 128, m0 = blockIdx.y * 128;
  f32x4 acc[4][4] = {};
  int seg0 = wave*2048 + lane*16;
  int ar = lane & 15, kq = (lane >> 4) * 8;

  for (int k0=0; k0<K; k0+=32){
    #pragma unroll
    for (int i=0;i<2;i++){
      int seg = seg0 + i*1024;
      int e = seg >> 1; int row = e >> 5; int kk = e & 31;
      gl2lds16(A  + (size_t)(m0+row)*lda + k0 + kk, (char*)As + seg);
      gl2lds16(BT + (size_t)(n0+row)*K   + k0 + kk, (char*)Bs + seg);
    }
    __syncthreads();
    half8 af[4], bf[4];
    #pragma unroll
    for (int mi=0;mi<4;mi++) af[mi] = *(const half8*)&As[(wm*64 + mi*16 + ar)*32 + kq];
    #pragma unroll
    for (int ni=0;ni<4;ni++) bf[ni] = *(const half8*)&Bs[(wn*64 + ni*16 + ar)*32 + kq];
    #pragma unroll
    for (int mi=0;mi<4;mi++)
      #pragma unroll
      for (int ni=0;ni<4;ni++)
        acc[mi][ni] = __builtin_amdgcn_mfma_f32_16x16x32_f16(af[mi], bf[ni], acc[mi][ni], 0, 0, 0);
    __syncthreads();
  }
  int rb = (lane >> 4) * 4, cb = lane & 15;
  #pragma unroll
  for (int ni=0;ni<4;ni++){
    int cn = n0 + wn*64 + ni*16 + cb;
    float bz = bias[cn];
    #pragma unroll
    for (int mi=0;mi<4;mi++){
      int rm = m0 + wm*64 + mi*16 + rb;
      #pragma unroll
      for (int r=0;r<4;r++){
        float v = acc[mi][ni][r] + bz;
        if (ACT==1) v = 0.5f*v*(1.0f+erff(v*0.70710678118f));
        if (OUT16) Ch[(size_t)(rm+r)*ldc + cn] = (f16)v;
        else       Cf[(size_t)(rm+r)*ldc + cn] = v;
      }
    }
  }
}

// ---------------- beta/g projections ----------------
__global__ __launch_bounds__(256) void betag_kernel(
    const float* __restrict__ x, const float* __restrict__ Wb, const float* __restrict__ bb,
    const float* __restrict__ Wg, const float* __restrict__ bg,
    const int* __restrict__ mask, float* __restrict__ beta, float* __restrict__ g)
{
  __shared__ float Ws[384*25];
  for (int idx = threadIdx.x; idx < 384*12; idx += 256){
    int k = idx/12, j = idx - k*12;
    Ws[k*25+j]    = Wb[idx];
    Ws[k*25+12+j] = Wg[idx];
  }
  __syncthreads();
  int wv = threadIdx.x>>6, lane = threadIdx.x&63;
  int row = blockIdx.x*4 + wv;
  const float* xr = x + (size_t)row*DD;
  float accb[12], accg[12];
  #pragma unroll
  for (int j=0;j<12;j++){ accb[j]=0.f; accg[j]=0.f; }
  #pragma unroll
  for (int i=0;i<6;i++){
    int k = lane + 64*i;
    float xv = xr[k];
    const float* wr = &Ws[k*25];
    #pragma unroll
    for (int j=0;j<12;j++){ accb[j] += xv*wr[j]; accg[j] += xv*wr[12+j]; }
  }
  #pragma unroll
  for (int j=0;j<12;j++){
    #pragma unroll
    for (int off=32; off>=1; off>>=1){
      accb[j]+=__shfl_xor(accb[j],off);
      accg[j]+=__shfl_xor(accg[j],off);
    }
  }
  if (lane==0){
    float mk = (float)mask[row];
    #pragma unroll
    for (int j=0;j<12;j++){
      beta[(size_t)row*HH + j] = sigmoidf_(accb[j]+bb[j]) * mk;
      g[(size_t)row*HH + j]    = sigmoidf_(accg[j]+bg[j]);
    }
  }
}

// ---------------- DeltaNet dual-state scan ----------------
// One wave (=block) per (b,h). Lanes 0-31 fast state, 32-63 slow; lane owns col=lane&31.
// qkv layout [row][1152]: q[0:384] k[384:768] v[768:1152]; out written in-place over q.
// k-norm fused at staging. NO cross-lane ops in the step loop (a per-step ds_swizzle
// would force lgkmcnt(0), draining the LDS prefetch pipeline every step — R5 lesson).
// Per-state outputs go to LDS Of[s][lane]; fast/slow g-mix happens in a per-tile
// combine pass (one drain per 32 steps).
__global__ __launch_bounds__(64) void scan_kernel(
  f16* qkv,
  const float* __restrict__ bp, const float* __restrict__ gp,
  const float* __restrict__ flp, const float* __restrict__ slp)
{
  __shared__ float Kf[2][TB][32];
  __shared__ float Qf[2][TB][32];
  __shared__ float Vf[2][TB][32];
  __shared__ float Bg[2][2][TB];
  __shared__ float Of[TB][64];
  int blk = blockIdx.x;
  int b = blk / HH, h = blk - b*HH;
  int lane = threadIdx.x;
  int col = lane & 31;
  float a = sigmoidf_((lane < 32) ? flp[h] : slp[h]);
  f32x2 a2 = {a, a};
  f32x2 S2[16];
  #pragma unroll
  for (int j=0;j<16;j++) S2[j] = (f32x2){0.f,0.f};
  size_t base = ((size_t)b*SS)*LDX + (size_t)h*DKK;
  f16* qb = qkv + base;                       // in-place out; aliases loads
  const f16* kb = qkv + base + 384;
  const f16* vb = qkv + base + 768;
  const float* bbp = bp + ((size_t)b*SS)*HH + h;
  const float* gbp = gp + ((size_t)b*SS)*HH + h;

  int st0 = lane >> 2, part = lane & 3;
  uint4 kv[2], qv[2], vv[2]; float bgv;

  #define LOADG(T0) do {                                                       \
    _Pragma("unroll")                                                          \
    for (int r=0;r<2;r++){                                                     \
      int st = (T0) + r*16 + st0;                                              \
      size_t off = (size_t)st*LDX + part*8;                                    \
      kv[r] = *(const uint4*)(kb + off);                                       \
      qv[r] = *(const uint4*)(qb + off);                                       \
      vv[r] = *(const uint4*)(vb + off);                                       \
    }                                                                          \
    int tb_ = (T0) + (lane & 31);                                              \
    bgv = (lane < 32) ? bbp[(size_t)tb_*HH] : gbp[(size_t)tb_*HH];             \
  } while(0)

  #define STAGE(BUF) do {                                                      \
    _Pragma("unroll")                                                          \
    for (int r=0;r<2;r++){                                                     \
      int s = r*16 + st0;                                                      \
      float kf[8], qf[8], vf[8];                                               \
      kf[0]=h2f_lo(kv[r].x); kf[1]=h2f_hi(kv[r].x); kf[2]=h2f_lo(kv[r].y);     \
      kf[3]=h2f_hi(kv[r].y); kf[4]=h2f_lo(kv[r].z); kf[5]=h2f_hi(kv[r].z);     \
      kf[6]=h2f_lo(kv[r].w); kf[7]=h2f_hi(kv[r].w);                            \
      qf[0]=h2f_lo(qv[r].x); qf[1]=h2f_hi(qv[r].x); qf[2]=h2f_lo(qv[r].y);     \
      qf[3]=h2f_hi(qv[r].y); qf[4]=h2f_lo(qv[r].z); qf[5]=h2f_hi(qv[r].z);     \
      qf[6]=h2f_lo(qv[r].w); qf[7]=h2f_hi(qv[r].w);                            \
      vf[0]=h2f_lo(vv[r].x); vf[1]=h2f_hi(vv[r].x); vf[2]=h2f_lo(vv[r].y);     \
      vf[3]=h2f_hi(vv[r].y); vf[4]=h2f_lo(vv[r].z); vf[5]=h2f_hi(vv[r].z);     \
      vf[6]=h2f_lo(vv[r].w); vf[7]=h2f_hi(vv[r].w);                            \
      float ss = 0.f;                                                          \
      _Pragma("unroll")                                                        \
      for (int i=0;i<8;i++) ss += kf[i]*kf[i];                                 \
      ss += __shfl_xor(ss, 1); ss += __shfl_xor(ss, 2);                        \
      float sc = 1.0f/(sqrtf(ss)+1e-6f);                                       \
      float4 t;                                                                \
      t.x=kf[0]*sc; t.y=kf[1]*sc; t.z=kf[2]*sc; t.w=kf[3]*sc;                  \
      *(float4*)&Kf[BUF][s][part*8] = t;                                       \
      t.x=kf[4]*sc; t.y=kf[5]*sc; t.z=kf[6]*sc; t.w=kf[7]*sc;                  \
      *(float4*)&Kf[BUF][s][part*8+4] = t;                                     \
      t.x=qf[0]; t.y=qf[1]; t.z=qf[2]; t.w=qf[3];                              \
      *(float4*)&Qf[BUF][s][part*8] = t;                                       \
      t.x=qf[4]; t.y=qf[5]; t.z=qf[6]; t.w=qf[7];                              \
      *(float4*)&Qf[BUF][s][part*8+4] = t;                                     \
      t.x=vf[0]; t.y=vf[1]; t.z=vf[2]; t.w=vf[3];                              \
      *(float4*)&Vf[BUF][s][part*8] = t;                                       \
      t.x=vf[4]; t.y=vf[5]; t.z=vf[6]; t.w=vf[7];                              \
      *(float4*)&Vf[BUF][s][part*8+4] = t;                                     \
    }                                                                          \
    Bg[BUF][lane>>5][lane&31] = bgv;                                           \
  } while(0)

  #define LDSTEP(BUF,S,KR,QR,VT,BT) do {                                       \
    const float4* k4_ = (const float4*)&Kf[BUF][S][0];                         \
    const float4* q4_ = (const float4*)&Qf[BUF][S][0];                         \
    _Pragma("unroll")                                                          \
    for (int j=0;j<8;j++){ KR[j]=k4_[j]; QR[j]=q4_[j]; }                       \
    VT = Vf[BUF][S][col]; BT = Bg[BUF][0][S];                                  \
  } while(0)

  #define STEP(KR,QR,VT,BT,S) do {                                            \
    const f32x2* k2_ = (const f32x2*)KR;                                       \
    const f32x2* q2_ = (const f32x2*)QR;                                       \
    f32x2 rA={0.f,0.f},rB={0.f,0.f},rC={0.f,0.f},rD={0.f,0.f};                 \
    _Pragma("unroll")                                                          \
    for (int j=0;j<16;j+=4){                                                   \
      rA += S2[j+0]*k2_[j+0]; rB += S2[j+1]*k2_[j+1];                          \
      rC += S2[j+2]*k2_[j+2]; rD += S2[j+3]*k2_[j+3]; }                        \
    f32x2 rr = (rA+rB)+(rC+rD);                                                \
    float rf = rr.x + rr.y;                                                    \
    float c_ = (BT)*((VT) - rf);                                               \
    f32x2 c2 = {c_, c_};                                                       \
    _Pragma("unroll")                                                          \
    for (int j=0;j<16;j++) S2[j] = a2*S2[j] + c2*k2_[j];                       \
    f32x2 oA={0.f,0.f},oB={0.f,0.f},oC={0.f,0.f},oD={0.f,0.f};                 \
    _Pragma("unroll")                                                          \
    for (int j=0;j<16;j+=4){                                                   \
      oA += S2[j+0]*q2_[j+0]; oB += S2[j+1]*q2_[j+1];                          \
      oC += S2[j+2]*q2_[j+2]; oD += S2[j+3]*q2_[j+3]; }                        \
    f32x2 oo = (oA+oB)+(oC+oD);                                                \
    Of[S][lane] = oo.x + oo.y;                                                 \
  } while(0)

  // per-tile fast/slow mix + global store (one lgkm drain per tile, not per step)
  #define COMBINE(BUF,T0) do {                                                 \
    _Pragma("unroll")                                                          \
    for (int i=0;i<16;i++){                                                    \
      int idx = i*64 + lane;                                                   \
      int s_ = idx >> 5, c_ = idx & 31;                                        \
      float fv = Of[s_][c_];                                                   \
      float sv = Of[s_][c_+32];                                                \
      float gv = Bg[BUF][1][s_];                                               \
      qb[(size_t)((T0)+s_)*LDX + c_] = (f16)(gv*fv + (1.0f-gv)*sv);            \
    }                                                                          \
  } while(0)

  LOADG(0);
  STAGE(0);
  __syncthreads();

  float4 kA[8], qA[8], kB[8], qB[8];
  float vA, bA, vB, bB;

  for (int tile=0; tile<SS/TB; tile++){
    int buf = tile & 1;
    if (tile < SS/TB-1) LOADG((tile+1)*TB);   // global prefetch of next tile
    LDSTEP(buf, 0, kA, qA, vA, bA);
    #pragma unroll
    for (int s=0; s<TB; s+=2){
      if (s+1 < TB) LDSTEP(buf, s+1, kB, qB, vB, bB);
      STEP(kA, qA, vA, bA, s);
      if (s+2 < TB) LDSTEP(buf, s+2, kA, qA, vA, bA);
      STEP(kB, qB, vB, bB, s+1);
    }
    if (tile < SS/TB-1) STAGE(1-buf);
    COMBINE(buf, tile*TB);
    __syncthreads();
  }
  #undef LOADG
  #undef STAGE
  #undef LDSTEP
  #undef STEP
  #undef COMBINE
}

// ---------------- masked mean-pool + L2 normalize ----------------
__global__ __launch_bounds__(384) void pool_kernel(
    const float* __restrict__ x, const int* __restrict__ mask, float* __restrict__ out)
{
  __shared__ float red[384];
  __shared__ float tot;
  int b = blockIdx.x, d = threadIdx.x;
  const float* xb = x + (size_t)b*SS*DD;
  const int* mb = mask + b*SS;
  float s=0.f, sm=0.f;
  for (int t=0;t<SS;t++){ float m=(float)mb[t]; s += xb[(size_t)t*DD+d]*m; sm += m; }
  float emb = s / fmaxf(sm, 1e-9f);
  red[d] = emb*emb;
  __syncthreads();
  for (int off=192; off>=3; off>>=1){
    if (d < off) red[d] += red[d+off];
    __syncthreads();
  }
  if (d==0) tot = red[0]+red[1]+red[2];
  __syncthreads();
  out[(size_t)b*DD + d] = emb * rsqrtf(tot);
}

extern "C" void kernel_launch(void* const* d_in, const int* in_sizes, int n_in,
                              void* d_out, int out_size, void* d_ws, size_t ws_size,
                              hipStream_t stream)
{
  const int*   ids  = (const int*)d_in[0];
  const int*   amask= (const int*)d_in[1];
  const float* we   = (const float*)d_in[2];
  const float* pe   = (const float*)d_in[3];
  const float* te   = (const float*)d_in[4];
  const float* elnw = (const float*)d_in[5];
  const float* elnb = (const float*)d_in[6];
  const float* Wq   = (const float*)d_in[7];
  const float* bq   = (const float*)d_in[8];
  const float* Wk   = (const float*)d_in[9];
  const float* bk   = (const float*)d_in[10];
  const float* Wv   = (const float*)d_in[11];
  const float* bv   = (const float*)d_in[12];
  const float* Wb   = (const float*)d_in[13];
  const float* bb   = (const float*)d_in[14];
  const float* Wg   = (const float*)d_in[15];
  const float* bgp  = (const float*)d_in[16];
  const float* Wo   = (const float*)d_in[17];
  const float* bo   = (const float*)d_in[18];
  const float* fl   = (const float*)d_in[19];
  const float* sl   = (const float*)d_in[20];
  const float* alnw = (const float*)d_in[21];
  const float* alnb = (const float*)d_in[22];
  const float* W1   = (const float*)d_in[23];
  const float* b1   = (const float*)d_in[24];
  const float* W2   = (const float*)d_in[25];
  const float* b2   = (const float*)d_in[26];
  const float* flnw = (const float*)d_in[27];
  const float* flnb = (const float*)d_in[28];
  float* out = (float*)d_out;
  float* w = (float*)d_ws;

  // workspace (float slots)
  float* x    = w;                      // 12,582,912 f
  f16*  xh   = (f16*)(w + 12582912);    // 12,582,912 h (6,291,456 f)
  f16*  qkvh = (f16*)(w + 18874368);    // 37,748,736 h (18,874,368 f)  [row][1152]
  float* f2   = w + 37748736;           //  6,291,456 f (chunk out; beta/g overlay)
  float* beta = f2;                     //    393,216 f
  float* gbuf = f2 + 393216;            //    393,216 f
  f16*  wt   = (f16*)(w + 44040192);    //  1,769,472 h (884,736 f)
  float* bqkv = w + 44924928;           //      6,912 f
  f16*  hbf  = qkvh;                    // FFN hidden chunk 16384x1536 h overlays qkv
  // total 44,931,840 f = 179.7 MB

  embed_ln_kernel<<<MROWS/4, 256, 0, stream>>>(ids, we, pe, te, elnw, elnb, x, xh);
  biaspack_kernel<<<27,256,0,stream>>>(bq, bk, bv, bqkv);

  for (int l=0;l<LL;l++){
    wtrans_kernel<<<1728,256,0,stream>>>(
        Wq + (size_t)l*147456, Wk + (size_t)l*147456, Wv + (size_t)l*147456,
        Wo + (size_t)l*147456, W1 + (size_t)l*589824, W2 + (size_t)l*589824, wt);

    // fused QKV: [32768 x 1152] = xh @ [Wq|Wk|Wv]^T
    gemm_f16<0,1><<<dim3(9,256),256,0,stream>>>(xh, wt, bqkv + l*LDX, nullptr, qkvh,
                                                MROWS, LDX, DD, DD, LDX);

    betag_kernel<<<MROWS/4,256,0,stream>>>(x, Wb + (size_t)l*DD*HH, bb + l*HH,
                                           Wg + (size_t)l*DD*HH, bgp + l*HH,
                                           amask, beta, gbuf);
    scan_kernel<<<BB*HH,64,0,stream>>>(qkvh, beta, gbuf, fl + l*HH, sl + l*HH);

    // o-proj: A = attn-out = qkv[:,0:384] (lda=1152)
    for (int c=0;c<2;c++){
      gemm_f16<0,0><<<dim3(3,128),256,0,stream>>>(qkvh + (size_t)c*16384*LDX, wt+442368,
                                                  bo+l*DD, f2, nullptr, 16384, DD, DD, LDX, DD);
      add_ln_kernel<<<4096,256,0,stream>>>(x, xh, f2, alnw+l*DD, alnb+l*DD, c*16384);
    }
    // FFN (qkv dead -> hidden overlays it)
    for (int c=0;c<2;c++){
      gemm_f16<1,1><<<dim3(12,128),256,0,stream>>>(xh + (size_t)c*16384*DD, wt+589824,
                                                   b1+l*FFF, nullptr, hbf, 16384, FFF, DD, DD, FFF);
      gemm_f16<0,0><<<dim3(3,128),256,0,stream>>>(hbf, wt+1179648, b2+l*DD, f2, nullptr,
                                                  16384, DD, FFF, FFF, DD);
      add_ln_kernel<<<4096,256,0,stream>>>(x, xh, f2, flnw+l*DD, flnb+l*DD, c*16384);
    }
  }

  pool_kernel<<<BB,384,0,stream>>>(x, amask, out);
}